// Round 1
// baseline (14272.708 us; speedup 1.0000x reference)
//
#include <hip/hip_runtime.h>
#include <hip/hip_bf16.h>

#define NEG_SLOPE 0.2f

__device__ __forceinline__ float lrelu(float v) { return v > 0.f ? v : NEG_SLOPE * v; }

__device__ __forceinline__ void atomAddF(float* p, float v) {
    unsafeAtomicAdd(p, v);   // HW global_atomic_add_f32 on gfx950
}

// Detect whether edge_index arrived as int64 (odd 32-bit words all zero) or int32.
__global__ void k_detect(const int* __restrict__ ei32, int npairs, int* flag) {
    __shared__ int found;
    if (threadIdx.x == 0) found = 0;
    __syncthreads();
    for (int i = threadIdx.x; i < npairs; i += blockDim.x) {
        if (ei32[2 * i + 1] != 0) found = 1;
    }
    __syncthreads();
    if (threadIdx.x == 0) *flag = found ? 0 : 1;   // 1 => int64
}

__device__ __forceinline__ void load_edge(const void* ei, int f64, int e, int E, int& s, int& d) {
    if (f64) {
        const long long* p = (const long long*)ei;
        s = (int)p[e];
        d = (int)p[(long long)E + e];
    } else {
        const int* p = (const int*)ei;
        s = p[e];
        d = p[E + e];
    }
}

// xw1[N,128] = X[N,128] @ W1[128,128]
__global__ __launch_bounds__(256) void k_gemm1(const float* __restrict__ X,
                                               const float* __restrict__ W,
                                               float* __restrict__ XW, int N) {
    __shared__ float sX[64][68];
    __shared__ float sW[64 * 128];
    const int t = threadIdx.x;
    const int row0 = blockIdx.x * 64;
    const int tx = t & 15, ty = t >> 4;

    float acc[4][8];
#pragma unroll
    for (int i = 0; i < 4; i++)
#pragma unroll
        for (int j = 0; j < 8; j++) acc[i][j] = 0.f;

    for (int kt = 0; kt < 128; kt += 64) {
        {
            int r = t >> 2, ks = (t & 3) * 16;
            int row = row0 + r;
            if (row >= N) row = N - 1;
            const float4* xg = (const float4*)(X + (size_t)row * 128 + kt + ks);
            float4* xs = (float4*)&sX[r][ks];
#pragma unroll
            for (int j = 0; j < 4; j++) xs[j] = xg[j];

            const float4* wg = (const float4*)(W + (size_t)kt * 128);
            float4* wsm = (float4*)sW;
#pragma unroll
            for (int i = 0; i < 8; i++) wsm[t + 256 * i] = wg[t + 256 * i];
        }
        __syncthreads();
#pragma unroll 4
        for (int k = 0; k < 64; k++) {
            float xv[4];
#pragma unroll
            for (int i = 0; i < 4; i++) xv[i] = sX[ty * 4 + i][k];
            const float4 wa = *(const float4*)&sW[k * 128 + tx * 8];
            const float4 wb = *(const float4*)&sW[k * 128 + tx * 8 + 4];
            float w[8] = {wa.x, wa.y, wa.z, wa.w, wb.x, wb.y, wb.z, wb.w};
#pragma unroll
            for (int i = 0; i < 4; i++)
#pragma unroll
                for (int j = 0; j < 8; j++) acc[i][j] += xv[i] * w[j];
        }
        __syncthreads();
    }

#pragma unroll
    for (int i = 0; i < 4; i++) {
        int row = row0 + ty * 4 + i;
        if (row < N) {
            float4 o1 = {acc[i][0], acc[i][1], acc[i][2], acc[i][3]};
            float4 o2 = {acc[i][4], acc[i][5], acc[i][6], acc[i][7]};
            float4* og = (float4*)(XW + (size_t)row * 128 + tx * 8);
            og[0] = o1;
            og[1] = o2;
        }
    }
}

// per (node, head): a_src, a_dst, denom = exp(lrelu(a_src+a_dst))  (self-loop term)
__global__ void k_attn1(const float* __restrict__ XW, const float* __restrict__ att_s,
                        const float* __restrict__ att_d, float* __restrict__ aS,
                        float* __restrict__ aD, float* __restrict__ den, int N) {
    int t = blockIdx.x * blockDim.x + threadIdx.x;
    if (t >= N * 4) return;
    int n = t >> 2, h = t & 3;
    const float4* xr = (const float4*)(XW + (size_t)n * 128 + h * 32);
    const float4* ar = (const float4*)(att_s + h * 32);
    const float4* dr = (const float4*)(att_d + h * 32);
    float ss = 0.f, sd = 0.f;
#pragma unroll
    for (int j = 0; j < 8; j++) {
        float4 x4 = xr[j], a4 = ar[j], d4 = dr[j];
        ss += x4.x * a4.x + x4.y * a4.y + x4.z * a4.z + x4.w * a4.w;
        sd += x4.x * d4.x + x4.y * d4.y + x4.z * d4.z + x4.w * d4.w;
    }
    aS[t] = ss;
    aD[t] = sd;
    den[t] = __expf(lrelu(ss + sd));
}

__global__ void k_edge_denom1(const void* __restrict__ ei, const int* __restrict__ flag,
                              const float* __restrict__ aS, const float* __restrict__ aD,
                              float* __restrict__ den, int E) {
    int t = blockIdx.x * blockDim.x + threadIdx.x;
    if (t >= E * 4) return;
    int e = t >> 2, h = t & 3;
    int s, d;
    load_edge(ei, *flag, e, E, s, d);
    float w = __expf(lrelu(aS[s * 4 + h] + aD[d * 4 + h]));
    atomAddF(&den[d * 4 + h], w);
}

__global__ void k_edge_msg1(const void* __restrict__ ei, const int* __restrict__ flag,
                            const float* __restrict__ aS, const float* __restrict__ aD,
                            const float* __restrict__ den, const float* __restrict__ XW,
                            float* __restrict__ OUT, int E) {
    int t = blockIdx.x * blockDim.x + threadIdx.x;
    if (t >= E * 8) return;
    int e = t >> 3, sub = t & 7;
    int h = sub >> 1;
    int c0 = h * 32 + (sub & 1) * 16;
    int s, d;
    load_edge(ei, *flag, e, E, s, d);
    float w = __expf(lrelu(aS[s * 4 + h] + aD[d * 4 + h]));
    float alpha = w / den[d * 4 + h];
    const float4* xs = (const float4*)(XW + (size_t)s * 128 + c0);
    float* o = OUT + (size_t)d * 128 + c0;
#pragma unroll
    for (int j = 0; j < 4; j++) {
        float4 v = xs[j];
        atomAddF(o + 4 * j + 0, alpha * v.x);
        atomAddF(o + 4 * j + 1, alpha * v.y);
        atomAddF(o + 4 * j + 2, alpha * v.z);
        atomAddF(o + 4 * j + 3, alpha * v.w);
    }
}

// B = relu(OUT + alpha_self * XW + b1)
__global__ void k_finish1(const float* __restrict__ XW, const float* __restrict__ aS,
                          const float* __restrict__ aD, const float* __restrict__ den,
                          const float* __restrict__ b1, float* __restrict__ B, int N) {
    int t = blockIdx.x * blockDim.x + threadIdx.x;
    if (t >= N * 32) return;
    int n = t >> 5, q = t & 31;
    int c0 = q * 4, h = q >> 3;
    float as = aS[n * 4 + h], ad = aD[n * 4 + h], dn = den[n * 4 + h];
    float aself = __expf(lrelu(as + ad)) / dn;
    float4 o = *(float4*)(B + (size_t)n * 128 + c0);
    float4 x4 = *(const float4*)(XW + (size_t)n * 128 + c0);
    float4 b4 = *(const float4*)(b1 + c0);
    float4 r;
    r.x = fmaxf(o.x + aself * x4.x + b4.x, 0.f);
    r.y = fmaxf(o.y + aself * x4.y + b4.y, 0.f);
    r.z = fmaxf(o.z + aself * x4.z + b4.z, 0.f);
    r.w = fmaxf(o.w + aself * x4.w + b4.w, 0.f);
    *(float4*)(B + (size_t)n * 128 + c0) = r;
}

// xw2[N,40] = H[N,128] @ W2[128,40]
__global__ __launch_bounds__(256) void k_gemm2(const float* __restrict__ H,
                                               const float* __restrict__ W2,
                                               float* __restrict__ XW2, int N) {
    __shared__ float sH[64][132];
    __shared__ float sW2[128 * 40];
    const int t = threadIdx.x;
    const int row0 = blockIdx.x * 64;
    {
        int r = t >> 2, ks = (t & 3) * 32;
        int row = row0 + r;
        if (row >= N) row = N - 1;
        const float4* hg = (const float4*)(H + (size_t)row * 128 + ks);
        float4* hs = (float4*)&sH[r][ks];
#pragma unroll
        for (int j = 0; j < 8; j++) hs[j] = hg[j];
        const float4* wg = (const float4*)W2;
        float4* wsm = (float4*)sW2;
#pragma unroll
        for (int i = 0; i < 5; i++) wsm[t + 256 * i] = wg[t + 256 * i];
    }
    __syncthreads();
    int row = t >> 2, cg = t & 3;
    float acc[10];
#pragma unroll
    for (int j = 0; j < 10; j++) acc[j] = 0.f;
#pragma unroll 4
    for (int k = 0; k < 128; k++) {
        float a = sH[row][k];
#pragma unroll
        for (int j = 0; j < 10; j++) acc[j] += a * sW2[k * 40 + cg * 10 + j];
    }
    int grow = row0 + row;
    if (grow < N) {
        float* o = XW2 + (size_t)grow * 40 + cg * 10;
#pragma unroll
        for (int j = 0; j < 10; j++) o[j] = acc[j];
    }
}

__global__ void k_attn2(const float* __restrict__ XW2, const float* __restrict__ att_s,
                        const float* __restrict__ att_d, float* __restrict__ aS,
                        float* __restrict__ aD, float* __restrict__ den, int N) {
    int n = blockIdx.x * blockDim.x + threadIdx.x;
    if (n >= N) return;
    const float4* xr = (const float4*)(XW2 + (size_t)n * 40);
    float ss = 0.f, sd = 0.f;
#pragma unroll
    for (int j = 0; j < 10; j++) {
        float4 x4 = xr[j];
        float4 a4 = ((const float4*)att_s)[j];
        float4 d4 = ((const float4*)att_d)[j];
        ss += x4.x * a4.x + x4.y * a4.y + x4.z * a4.z + x4.w * a4.w;
        sd += x4.x * d4.x + x4.y * d4.y + x4.z * d4.z + x4.w * d4.w;
    }
    aS[n] = ss;
    aD[n] = sd;
    den[n] = __expf(lrelu(ss + sd));
}

__global__ void k_edge_denom2(const void* __restrict__ ei, const int* __restrict__ flag,
                              const float* __restrict__ aS, const float* __restrict__ aD,
                              float* __restrict__ den, int E) {
    int e = blockIdx.x * blockDim.x + threadIdx.x;
    if (e >= E) return;
    int s, d;
    load_edge(ei, *flag, e, E, s, d);
    float w = __expf(lrelu(aS[s] + aD[d]));
    atomAddF(&den[d], w);
}

__global__ void k_edge_msg2(const void* __restrict__ ei, const int* __restrict__ flag,
                            const float* __restrict__ aS, const float* __restrict__ aD,
                            const float* __restrict__ den, const float* __restrict__ XW2,
                            float* __restrict__ OUT, int E) {
    int t = blockIdx.x * blockDim.x + threadIdx.x;
    if (t >= E * 4) return;
    int e = t >> 2, q = t & 3;
    int c0 = q * 10;
    int s, d;
    load_edge(ei, *flag, e, E, s, d);
    float w = __expf(lrelu(aS[s] + aD[d]));
    float alpha = w / den[d];
    const float2* xs = (const float2*)(XW2 + (size_t)s * 40 + c0);
    float* o = OUT + (size_t)d * 40 + c0;
#pragma unroll
    for (int j = 0; j < 5; j++) {
        float2 v = xs[j];
        atomAddF(o + 2 * j + 0, alpha * v.x);
        atomAddF(o + 2 * j + 1, alpha * v.y);
    }
}

__global__ void k_finish2(const float* __restrict__ XW2, const float* __restrict__ aS,
                          const float* __restrict__ aD, const float* __restrict__ den,
                          const float* __restrict__ b2, float* __restrict__ OUT, int N) {
    int t = blockIdx.x * blockDim.x + threadIdx.x;
    if (t >= N * 40) return;
    int n = t / 40;
    int c = t - n * 40;
    float aself = __expf(lrelu(aS[n] + aD[n])) / den[n];
    OUT[t] = OUT[t] + aself * XW2[t] + b2[c];
}

extern "C" void kernel_launch(void* const* d_in, const int* in_sizes, int n_in,
                              void* d_out, int out_size, void* d_ws, size_t ws_size,
                              hipStream_t stream) {
    const float* x   = (const float*)d_in[0];
    const void*  ei  = d_in[1];
    const float* W1  = (const float*)d_in[2];
    const float* as1 = (const float*)d_in[3];
    const float* ad1 = (const float*)d_in[4];
    const float* b1  = (const float*)d_in[5];
    const float* W2  = (const float*)d_in[6];
    const float* as2 = (const float*)d_in[7];
    const float* ad2 = (const float*)d_in[8];
    const float* b2  = (const float*)d_in[9];
    float* out = (float*)d_out;

    const int N = in_sizes[0] / 128;
    const int E = in_sizes[1] / 2;

    float* ws = (float*)d_ws;
    int* flag = (int*)d_ws;
    float* A   = ws + 4;                    // xw1, later reused as xw2
    float* Bb  = A + (size_t)N * 128;       // out1 accumulator / h
    float* aS1 = Bb + (size_t)N * 128;
    float* aD1 = aS1 + (size_t)N * 4;
    float* dn1 = aD1 + (size_t)N * 4;
    float* aS2 = dn1 + (size_t)N * 4;
    float* aD2 = aS2 + N;
    float* dn2 = aD2 + N;

    k_detect<<<1, 256, 0, stream>>>((const int*)ei, 1024, flag);

    const int gb = (N + 63) / 64;
    k_gemm1<<<gb, 256, 0, stream>>>(x, W1, A, N);
    k_attn1<<<(N * 4 + 255) / 256, 256, 0, stream>>>(A, as1, ad1, aS1, aD1, dn1, N);
    k_edge_denom1<<<(E * 4 + 255) / 256, 256, 0, stream>>>(ei, flag, aS1, aD1, dn1, E);
    hipMemsetAsync(Bb, 0, (size_t)N * 128 * sizeof(float), stream);
    k_edge_msg1<<<(E * 8 + 255) / 256, 256, 0, stream>>>(ei, flag, aS1, aD1, dn1, A, Bb, E);
    k_finish1<<<(N * 32 + 255) / 256, 256, 0, stream>>>(A, aS1, aD1, dn1, b1, Bb, N);

    k_gemm2<<<gb, 256, 0, stream>>>(Bb, W2, A, N);   // A := xw2 [N,40]
    k_attn2<<<(N + 255) / 256, 256, 0, stream>>>(A, as2, ad2, aS2, aD2, dn2, N);
    k_edge_denom2<<<(E + 255) / 256, 256, 0, stream>>>(ei, flag, aS2, aD2, dn2, E);
    hipMemsetAsync(out, 0, (size_t)N * 40 * sizeof(float), stream);
    k_edge_msg2<<<(E * 4 + 255) / 256, 256, 0, stream>>>(ei, flag, aS2, aD2, dn2, A, out, E);
    k_finish2<<<(N * 40 + 255) / 256, 256, 0, stream>>>(A, aS2, aD2, dn2, b2, out, N);
}

// Round 2
// 883.971 us; speedup vs baseline: 16.1461x; 16.1461x over previous
//
#include <hip/hip_runtime.h>
#include <hip/hip_bf16.h>

#define NEG_SLOPE 0.2f

__device__ __forceinline__ float lrelu(float v) { return v > 0.f ? v : NEG_SLOPE * v; }

// Detect whether edge_index arrived as int64 (odd 32-bit words all zero) or int32.
__global__ void k_detect(const int* __restrict__ ei32, int npairs, int* flag) {
    __shared__ int found;
    if (threadIdx.x == 0) found = 0;
    __syncthreads();
    for (int i = threadIdx.x; i < npairs; i += blockDim.x) {
        if (ei32[2 * i + 1] != 0) found = 1;
    }
    __syncthreads();
    if (threadIdx.x == 0) *flag = found ? 0 : 1;   // 1 => int64
}

__device__ __forceinline__ void load_edge(const void* ei, int f64, int e, int E, int& s, int& d) {
    if (f64) {
        const long long* p = (const long long*)ei;
        s = (int)p[e];
        d = (int)p[(long long)E + e];
    } else {
        const int* p = (const int*)ei;
        s = p[e];
        d = p[E + e];
    }
}

// ---------------- CSR build ----------------
__global__ void k_degree(const void* __restrict__ ei, const int* __restrict__ flag,
                         int* __restrict__ deg, int E) {
    int e = blockIdx.x * blockDim.x + threadIdx.x;
    if (e >= E) return;
    int s, d;
    load_edge(ei, *flag, e, E, s, d);
    atomicAdd(&deg[d], 1);
}

// Single-workgroup scan: offsets[0]=0; offsets[i+1]=sum(deg[0..i])
__global__ __launch_bounds__(1024) void k_scan(const int* __restrict__ deg,
                                               int* __restrict__ offsets, int N) {
    __shared__ int sdata[1024];
    int t = threadIdx.x;
    if (t == 0) offsets[0] = 0;
    int carry = 0;
    for (int base = 0; base < N; base += 4096) {
        int idx = base + t * 4;
        int v0 = (idx + 0 < N) ? deg[idx + 0] : 0;
        int v1 = (idx + 1 < N) ? deg[idx + 1] : 0;
        int v2 = (idx + 2 < N) ? deg[idx + 2] : 0;
        int v3 = (idx + 3 < N) ? deg[idx + 3] : 0;
        int s1 = v0 + v1, s2 = s1 + v2, s3 = s2 + v3;
        sdata[t] = s3;
        __syncthreads();
        for (int off = 1; off < 1024; off <<= 1) {
            int x = (t >= off) ? sdata[t - off] : 0;
            __syncthreads();
            sdata[t] += x;
            __syncthreads();
        }
        int total = sdata[1023];
        int excl = carry + ((t > 0) ? sdata[t - 1] : 0);
        if (idx + 0 < N) offsets[idx + 1] = excl + v0;
        if (idx + 1 < N) offsets[idx + 2] = excl + s1;
        if (idx + 2 < N) offsets[idx + 3] = excl + s2;
        if (idx + 3 < N) offsets[idx + 4] = excl + s3;
        carry += total;
        __syncthreads();
    }
}

__global__ void k_copy(const int* __restrict__ offsets, int* __restrict__ cursor, int N) {
    int n = blockIdx.x * blockDim.x + threadIdx.x;
    if (n < N) cursor[n] = offsets[n];
}

__global__ void k_scatter(const void* __restrict__ ei, const int* __restrict__ flag,
                          int* __restrict__ cursor, int* __restrict__ csr_src, int E) {
    int e = blockIdx.x * blockDim.x + threadIdx.x;
    if (e >= E) return;
    int s, d;
    load_edge(ei, *flag, e, E, s, d);
    int slot = atomicAdd(&cursor[d], 1);
    csr_src[slot] = s;
}

// ---------------- GEMMs (unchanged from R1) ----------------
__global__ __launch_bounds__(256) void k_gemm1(const float* __restrict__ X,
                                               const float* __restrict__ W,
                                               float* __restrict__ XW, int N) {
    __shared__ float sX[64][68];
    __shared__ float sW[64 * 128];
    const int t = threadIdx.x;
    const int row0 = blockIdx.x * 64;
    const int tx = t & 15, ty = t >> 4;

    float acc[4][8];
#pragma unroll
    for (int i = 0; i < 4; i++)
#pragma unroll
        for (int j = 0; j < 8; j++) acc[i][j] = 0.f;

    for (int kt = 0; kt < 128; kt += 64) {
        {
            int r = t >> 2, ks = (t & 3) * 16;
            int row = row0 + r;
            if (row >= N) row = N - 1;
            const float4* xg = (const float4*)(X + (size_t)row * 128 + kt + ks);
            float4* xs = (float4*)&sX[r][ks];
#pragma unroll
            for (int j = 0; j < 4; j++) xs[j] = xg[j];

            const float4* wg = (const float4*)(W + (size_t)kt * 128);
            float4* wsm = (float4*)sW;
#pragma unroll
            for (int i = 0; i < 8; i++) wsm[t + 256 * i] = wg[t + 256 * i];
        }
        __syncthreads();
#pragma unroll 4
        for (int k = 0; k < 64; k++) {
            float xv[4];
#pragma unroll
            for (int i = 0; i < 4; i++) xv[i] = sX[ty * 4 + i][k];
            const float4 wa = *(const float4*)&sW[k * 128 + tx * 8];
            const float4 wb = *(const float4*)&sW[k * 128 + tx * 8 + 4];
            float w[8] = {wa.x, wa.y, wa.z, wa.w, wb.x, wb.y, wb.z, wb.w};
#pragma unroll
            for (int i = 0; i < 4; i++)
#pragma unroll
                for (int j = 0; j < 8; j++) acc[i][j] += xv[i] * w[j];
        }
        __syncthreads();
    }

#pragma unroll
    for (int i = 0; i < 4; i++) {
        int row = row0 + ty * 4 + i;
        if (row < N) {
            float4 o1 = {acc[i][0], acc[i][1], acc[i][2], acc[i][3]};
            float4 o2 = {acc[i][4], acc[i][5], acc[i][6], acc[i][7]};
            float4* og = (float4*)(XW + (size_t)row * 128 + tx * 8);
            og[0] = o1;
            og[1] = o2;
        }
    }
}

__global__ __launch_bounds__(256) void k_gemm2(const float* __restrict__ H,
                                               const float* __restrict__ W2,
                                               float* __restrict__ XW2, int N) {
    __shared__ float sH[64][132];
    __shared__ float sW2[128 * 40];
    const int t = threadIdx.x;
    const int row0 = blockIdx.x * 64;
    {
        int r = t >> 2, ks = (t & 3) * 32;
        int row = row0 + r;
        if (row >= N) row = N - 1;
        const float4* hg = (const float4*)(H + (size_t)row * 128 + ks);
        float4* hs = (float4*)&sH[r][ks];
#pragma unroll
        for (int j = 0; j < 8; j++) hs[j] = hg[j];
        const float4* wg = (const float4*)W2;
        float4* wsm = (float4*)sW2;
#pragma unroll
        for (int i = 0; i < 5; i++) wsm[t + 256 * i] = wg[t + 256 * i];
    }
    __syncthreads();
    int row = t >> 2, cg = t & 3;
    float acc[10];
#pragma unroll
    for (int j = 0; j < 10; j++) acc[j] = 0.f;
#pragma unroll 4
    for (int k = 0; k < 128; k++) {
        float a = sH[row][k];
#pragma unroll
        for (int j = 0; j < 10; j++) acc[j] += a * sW2[k * 40 + cg * 10 + j];
    }
    int grow = row0 + row;
    if (grow < N) {
        float* o = XW2 + (size_t)grow * 40 + cg * 10;
#pragma unroll
        for (int j = 0; j < 10; j++) o[j] = acc[j];
    }
}

// ---------------- attention dots ----------------
__global__ void k_attn1(const float* __restrict__ XW, const float* __restrict__ att_s,
                        const float* __restrict__ att_d, float* __restrict__ aS,
                        float* __restrict__ aD, int N) {
    int t = blockIdx.x * blockDim.x + threadIdx.x;
    if (t >= N * 4) return;
    int n = t >> 2, h = t & 3;
    const float4* xr = (const float4*)(XW + (size_t)n * 128 + h * 32);
    const float4* ar = (const float4*)(att_s + h * 32);
    const float4* dr = (const float4*)(att_d + h * 32);
    float ss = 0.f, sd = 0.f;
#pragma unroll
    for (int j = 0; j < 8; j++) {
        float4 x4 = xr[j], a4 = ar[j], d4 = dr[j];
        ss += x4.x * a4.x + x4.y * a4.y + x4.z * a4.z + x4.w * a4.w;
        sd += x4.x * d4.x + x4.y * d4.y + x4.z * d4.z + x4.w * d4.w;
    }
    aS[t] = ss;
    aD[t] = sd;
}

__global__ void k_attn2(const float* __restrict__ XW2, const float* __restrict__ att_s,
                        const float* __restrict__ att_d, float* __restrict__ aS,
                        float* __restrict__ aD, int N) {
    int n = blockIdx.x * blockDim.x + threadIdx.x;
    if (n >= N) return;
    const float4* xr = (const float4*)(XW2 + (size_t)n * 40);
    float ss = 0.f, sd = 0.f;
#pragma unroll
    for (int j = 0; j < 10; j++) {
        float4 x4 = xr[j];
        float4 a4 = ((const float4*)att_s)[j];
        float4 d4 = ((const float4*)att_d)[j];
        ss += x4.x * a4.x + x4.y * a4.y + x4.z * a4.z + x4.w * a4.w;
        sd += x4.x * d4.x + x4.y * d4.y + x4.z * d4.z + x4.w * d4.w;
    }
    aS[n] = ss;
    aD[n] = sd;
}

// ---------------- gather-reduce denominators ----------------
__global__ void k_denom1(const int* __restrict__ offsets, const int* __restrict__ csr_src,
                         const float* __restrict__ aS, const float* __restrict__ aD,
                         float* __restrict__ idn, int N) {
    int t = blockIdx.x * blockDim.x + threadIdx.x;
    if (t >= N * 4) return;
    int n = t >> 2, h = t & 3;
    float ad = aD[t];
    float sum = __expf(lrelu(aS[t] + ad));   // self loop
    int b = offsets[n], e = offsets[n + 1];
    for (int i = b; i < e; i++) {
        int s = csr_src[i];
        sum += __expf(lrelu(aS[s * 4 + h] + ad));
    }
    idn[t] = 1.0f / sum;
}

__global__ void k_denom2(const int* __restrict__ offsets, const int* __restrict__ csr_src,
                         const float* __restrict__ aS, const float* __restrict__ aD,
                         float* __restrict__ idn, int N) {
    int n = blockIdx.x * blockDim.x + threadIdx.x;
    if (n >= N) return;
    float ad = aD[n];
    float sum = __expf(lrelu(aS[n] + ad));
    int b = offsets[n], e = offsets[n + 1];
    for (int i = b; i < e; i++) {
        int s = csr_src[i];
        sum += __expf(lrelu(aS[s] + ad));
    }
    idn[n] = 1.0f / sum;
}

// ---------------- gather-reduce messages (fused epilogues) ----------------
// Block of 128 threads = one destination node; thread = channel; h = c>>5.
__global__ __launch_bounds__(128) void k_msg1(const int* __restrict__ offsets,
                                              const int* __restrict__ csr_src,
                                              const float* __restrict__ aS,
                                              const float* __restrict__ aD,
                                              const float* __restrict__ idn,
                                              const float* __restrict__ A,
                                              const float* __restrict__ b1,
                                              float* __restrict__ H, int N) {
    int n = blockIdx.x;
    int c = threadIdx.x;
    int h = c >> 5;
    float adh = aD[n * 4 + h];
    float acc = __expf(lrelu(aS[n * 4 + h] + adh)) * A[(size_t)n * 128 + c];  // self
    int b = offsets[n], e = offsets[n + 1];
    for (int i = b; i < e; i++) {
        int s = csr_src[i];
        float w = __expf(lrelu(aS[s * 4 + h] + adh));
        acc += w * A[(size_t)s * 128 + c];
    }
    H[(size_t)n * 128 + c] = fmaxf(acc * idn[n * 4 + h] + b1[c], 0.f);
}

// 4 nodes per 256-thread block; wave per node, lanes 0..39 active.
__global__ __launch_bounds__(256) void k_msg2(const int* __restrict__ offsets,
                                              const int* __restrict__ csr_src,
                                              const float* __restrict__ aS,
                                              const float* __restrict__ aD,
                                              const float* __restrict__ idn,
                                              const float* __restrict__ XW2,
                                              const float* __restrict__ b2,
                                              float* __restrict__ OUT, int N) {
    int n = blockIdx.x * 4 + (threadIdx.x >> 6);
    int c = threadIdx.x & 63;
    if (n >= N || c >= 40) return;
    float adh = aD[n];
    float acc = __expf(lrelu(aS[n] + adh)) * XW2[(size_t)n * 40 + c];  // self
    int b = offsets[n], e = offsets[n + 1];
    for (int i = b; i < e; i++) {
        int s = csr_src[i];
        float w = __expf(lrelu(aS[s] + adh));
        acc += w * XW2[(size_t)s * 40 + c];
    }
    OUT[(size_t)n * 40 + c] = acc * idn[n] + b2[c];
}

extern "C" void kernel_launch(void* const* d_in, const int* in_sizes, int n_in,
                              void* d_out, int out_size, void* d_ws, size_t ws_size,
                              hipStream_t stream) {
    const float* x   = (const float*)d_in[0];
    const void*  ei  = d_in[1];
    const float* W1  = (const float*)d_in[2];
    const float* as1 = (const float*)d_in[3];
    const float* ad1 = (const float*)d_in[4];
    const float* b1  = (const float*)d_in[5];
    const float* W2  = (const float*)d_in[6];
    const float* as2 = (const float*)d_in[7];
    const float* ad2 = (const float*)d_in[8];
    const float* b2  = (const float*)d_in[9];
    float* out = (float*)d_out;

    const int N = in_sizes[0] / 128;
    const int E = in_sizes[1] / 2;

    // workspace layout (4-byte words)
    char* w = (char*)d_ws;
    int* flag      = (int*)w;                 w += 16;
    int* offsets   = (int*)w;                 w += (size_t)(N + 1) * 4;  // [N+1]
    int* cursor    = (int*)w;                 w += (size_t)N * 4;        // deg, then cursor
    int* csr_src   = (int*)w;                 w += (size_t)E * 4;
    float* aS1     = (float*)w;               w += (size_t)N * 4 * 4;
    float* aD1     = (float*)w;               w += (size_t)N * 4 * 4;
    float* idn1    = (float*)w;               w += (size_t)N * 4 * 4;
    float* aS2     = (float*)w;               w += (size_t)N * 4;
    float* aD2     = (float*)w;               w += (size_t)N * 4;
    float* idn2    = (float*)w;               w += (size_t)N * 4;
    float* A       = (float*)w;               w += (size_t)N * 128 * 4;  // xw1, later xw2
    float* H       = (float*)w;               // [N,128]

    k_detect<<<1, 256, 0, stream>>>((const int*)ei, 1024, flag);

    // CSR build (shared by both layers)
    hipMemsetAsync(cursor, 0, (size_t)N * 4, stream);
    k_degree<<<(E + 255) / 256, 256, 0, stream>>>(ei, flag, cursor, E);
    k_scan<<<1, 1024, 0, stream>>>(cursor, offsets, N);
    k_copy<<<(N + 255) / 256, 256, 0, stream>>>(offsets, cursor, N);
    k_scatter<<<(E + 255) / 256, 256, 0, stream>>>(ei, flag, cursor, csr_src, E);

    // layer 1
    const int gb = (N + 63) / 64;
    k_gemm1<<<gb, 256, 0, stream>>>(x, W1, A, N);
    k_attn1<<<(N * 4 + 255) / 256, 256, 0, stream>>>(A, as1, ad1, aS1, aD1, N);
    k_denom1<<<(N * 4 + 255) / 256, 256, 0, stream>>>(offsets, csr_src, aS1, aD1, idn1, N);
    k_msg1<<<N, 128, 0, stream>>>(offsets, csr_src, aS1, aD1, idn1, A, b1, H, N);

    // layer 2
    k_gemm2<<<gb, 256, 0, stream>>>(H, W2, A, N);   // A := xw2 [N,40]
    k_attn2<<<(N + 255) / 256, 256, 0, stream>>>(A, as2, ad2, aS2, aD2, N);
    k_denom2<<<(N + 255) / 256, 256, 0, stream>>>(offsets, csr_src, aS2, aD2, idn2, N);
    k_msg2<<<(N + 3) / 4, 256, 0, stream>>>(offsets, csr_src, aS2, aD2, idn2, A, b2, out, N);
}

// Round 3
// 673.402 us; speedup vs baseline: 21.1949x; 1.3127x over previous
//
#include <hip/hip_runtime.h>
#include <hip/hip_bf16.h>

#define NEG_SLOPE 0.2f

__device__ __forceinline__ float lrelu(float v) { return v > 0.f ? v : NEG_SLOPE * v; }

__device__ __forceinline__ unsigned short f2bf(float f) {
    unsigned u = __float_as_uint(f);
    unsigned r = (u + 0x7fffu + ((u >> 16) & 1u)) >> 16;   // RNE
    return (unsigned short)r;
}
__device__ __forceinline__ float bflo(unsigned p) { return __uint_as_float(p << 16); }
__device__ __forceinline__ float bfhi(unsigned p) { return __uint_as_float(p & 0xffff0000u); }

// Detect whether edge_index arrived as int64 (odd 32-bit words all zero) or int32.
__global__ void k_detect(const int* __restrict__ ei32, int npairs, int* flag) {
    __shared__ int found;
    if (threadIdx.x == 0) found = 0;
    __syncthreads();
    for (int i = threadIdx.x; i < npairs; i += blockDim.x) {
        if (ei32[2 * i + 1] != 0) found = 1;
    }
    __syncthreads();
    if (threadIdx.x == 0) *flag = found ? 0 : 1;   // 1 => int64
}

__device__ __forceinline__ void load_edge(const void* ei, int f64, int e, int E, int& s, int& d) {
    if (f64) {
        const long long* p = (const long long*)ei;
        s = (int)p[e];
        d = (int)p[(long long)E + e];
    } else {
        const int* p = (const int*)ei;
        s = p[e];
        d = p[E + e];
    }
}

// ---------------- CSR build ----------------
__global__ void k_degree(const void* __restrict__ ei, const int* __restrict__ flag,
                         int* __restrict__ deg, int E) {
    int e = blockIdx.x * blockDim.x + threadIdx.x;
    if (e >= E) return;
    int s, d;
    load_edge(ei, *flag, e, E, s, d);
    atomicAdd(&deg[d], 1);
}

// Single-workgroup scan, shfl-based: offsets[0]=0; offsets[i+1]=sum(deg[0..i])
__global__ __launch_bounds__(1024) void k_scan(const int* __restrict__ deg,
                                               int* __restrict__ offsets, int N) {
    __shared__ int wsums[16];
    __shared__ int chunk_total;
    const int t = threadIdx.x;
    const int lane = t & 63;
    const int wid = t >> 6;
    if (t == 0) offsets[0] = 0;
    int carry = 0;
    for (int base = 0; base < N; base += 4096) {
        int idx = base + t * 4;
        int v0 = (idx + 0 < N) ? deg[idx + 0] : 0;
        int v1 = (idx + 1 < N) ? deg[idx + 1] : 0;
        int v2 = (idx + 2 < N) ? deg[idx + 2] : 0;
        int v3 = (idx + 3 < N) ? deg[idx + 3] : 0;
        int s1 = v0 + v1, s2 = s1 + v2, s3 = s2 + v3;
        // wave inclusive scan of s3
        int inc = s3;
#pragma unroll
        for (int off = 1; off < 64; off <<= 1) {
            int y = __shfl_up(inc, off);
            if (lane >= off) inc += y;
        }
        if (lane == 63) wsums[wid] = inc;
        __syncthreads();
        if (wid == 0) {
            int v = (lane < 16) ? wsums[lane] : 0;
            int wi = v;
#pragma unroll
            for (int off = 1; off < 16; off <<= 1) {
                int y = __shfl_up(wi, off);
                if (lane >= off) wi += y;
            }
            if (lane < 16) wsums[lane] = wi - v;      // exclusive
            if (lane == 15) chunk_total = wi;
        }
        __syncthreads();
        int excl = carry + wsums[wid] + (inc - s3);   // exclusive prefix for this thread
        if (idx + 0 < N) offsets[idx + 1] = excl + v0;
        if (idx + 1 < N) offsets[idx + 2] = excl + s1;
        if (idx + 2 < N) offsets[idx + 3] = excl + s2;
        if (idx + 3 < N) offsets[idx + 4] = excl + s3;
        carry += chunk_total;
        __syncthreads();
    }
}

__global__ void k_copy(const int* __restrict__ offsets, int* __restrict__ cursor, int N) {
    int n = blockIdx.x * blockDim.x + threadIdx.x;
    if (n < N) cursor[n] = offsets[n];
}

__global__ void k_scatter(const void* __restrict__ ei, const int* __restrict__ flag,
                          int* __restrict__ cursor, int* __restrict__ csr_src, int E) {
    int e = blockIdx.x * blockDim.x + threadIdx.x;
    if (e >= E) return;
    int s, d;
    load_edge(ei, *flag, e, E, s, d);
    int slot = atomicAdd(&cursor[d], 1);
    csr_src[slot] = s;
}

// ---------------- GEMM1: xw1 = X @ W1, stored bf16 ----------------
__global__ __launch_bounds__(256) void k_gemm1(const float* __restrict__ X,
                                               const float* __restrict__ W,
                                               unsigned short* __restrict__ Abf, int N) {
    __shared__ float sX[64][68];
    __shared__ float sW[64 * 128];
    const int t = threadIdx.x;
    const int row0 = blockIdx.x * 64;
    const int tx = t & 15, ty = t >> 4;

    float acc[4][8];
#pragma unroll
    for (int i = 0; i < 4; i++)
#pragma unroll
        for (int j = 0; j < 8; j++) acc[i][j] = 0.f;

    for (int kt = 0; kt < 128; kt += 64) {
        {
            int r = t >> 2, ks = (t & 3) * 16;
            int row = row0 + r;
            if (row >= N) row = N - 1;
            const float4* xg = (const float4*)(X + (size_t)row * 128 + kt + ks);
            float4* xs = (float4*)&sX[r][ks];
#pragma unroll
            for (int j = 0; j < 4; j++) xs[j] = xg[j];

            const float4* wg = (const float4*)(W + (size_t)kt * 128);
            float4* wsm = (float4*)sW;
#pragma unroll
            for (int i = 0; i < 8; i++) wsm[t + 256 * i] = wg[t + 256 * i];
        }
        __syncthreads();
#pragma unroll 4
        for (int k = 0; k < 64; k++) {
            float xv[4];
#pragma unroll
            for (int i = 0; i < 4; i++) xv[i] = sX[ty * 4 + i][k];
            const float4 wa = *(const float4*)&sW[k * 128 + tx * 8];
            const float4 wb = *(const float4*)&sW[k * 128 + tx * 8 + 4];
            float w[8] = {wa.x, wa.y, wa.z, wa.w, wb.x, wb.y, wb.z, wb.w};
#pragma unroll
            for (int i = 0; i < 4; i++)
#pragma unroll
                for (int j = 0; j < 8; j++) acc[i][j] += xv[i] * w[j];
        }
        __syncthreads();
    }

#pragma unroll
    for (int i = 0; i < 4; i++) {
        int row = row0 + ty * 4 + i;
        if (row < N) {
            unsigned p[4];
#pragma unroll
            for (int j = 0; j < 4; j++)
                p[j] = (unsigned)f2bf(acc[i][2 * j]) | ((unsigned)f2bf(acc[i][2 * j + 1]) << 16);
            uint4* og = (uint4*)(Abf + (size_t)row * 128 + tx * 8);
            *og = make_uint4(p[0], p[1], p[2], p[3]);
        }
    }
}

// ---------------- GEMM2: xw2 = H @ W2, stored bf16 ----------------
__global__ __launch_bounds__(256) void k_gemm2(const float* __restrict__ H,
                                               const float* __restrict__ W2,
                                               unsigned short* __restrict__ X2bf, int N) {
    __shared__ float sH[64][132];
    __shared__ float sW2[128 * 40];
    const int t = threadIdx.x;
    const int row0 = blockIdx.x * 64;
    {
        int r = t >> 2, ks = (t & 3) * 32;
        int row = row0 + r;
        if (row >= N) row = N - 1;
        const float4* hg = (const float4*)(H + (size_t)row * 128 + ks);
        float4* hs = (float4*)&sH[r][ks];
#pragma unroll
        for (int j = 0; j < 8; j++) hs[j] = hg[j];
        const float4* wg = (const float4*)W2;
        float4* wsm = (float4*)sW2;
#pragma unroll
        for (int i = 0; i < 5; i++) wsm[t + 256 * i] = wg[t + 256 * i];
    }
    __syncthreads();
    int row = t >> 2, cg = t & 3;
    float acc[10];
#pragma unroll
    for (int j = 0; j < 10; j++) acc[j] = 0.f;
#pragma unroll 4
    for (int k = 0; k < 128; k++) {
        float a = sH[row][k];
#pragma unroll
        for (int j = 0; j < 10; j++) acc[j] += a * sW2[k * 40 + cg * 10 + j];
    }
    int grow = row0 + row;
    if (grow < N) {
        unsigned* o = (unsigned*)(X2bf + (size_t)grow * 40 + cg * 10);
#pragma unroll
        for (int j = 0; j < 5; j++)
            o[j] = (unsigned)f2bf(acc[2 * j]) | ((unsigned)f2bf(acc[2 * j + 1]) << 16);
    }
}

// ---------------- attention dots (from bf16) ----------------
__global__ void k_attn1(const unsigned short* __restrict__ Abf, const float* __restrict__ att_s,
                        const float* __restrict__ att_d, float* __restrict__ aS,
                        float* __restrict__ aD, int N) {
    int t = blockIdx.x * blockDim.x + threadIdx.x;
    if (t >= N * 4) return;
    int n = t >> 2, h = t & 3;
    const uint4* xr = (const uint4*)(Abf + (size_t)n * 128 + h * 32);
    float ss = 0.f, sd = 0.f;
#pragma unroll
    for (int j = 0; j < 4; j++) {
        uint4 p = xr[j];
        float xv[8] = {bflo(p.x), bfhi(p.x), bflo(p.y), bfhi(p.y),
                       bflo(p.z), bfhi(p.z), bflo(p.w), bfhi(p.w)};
        const float* as_ = att_s + h * 32 + j * 8;
        const float* ad_ = att_d + h * 32 + j * 8;
#pragma unroll
        for (int q = 0; q < 8; q++) {
            ss += xv[q] * as_[q];
            sd += xv[q] * ad_[q];
        }
    }
    aS[t] = ss;
    aD[t] = sd;
}

__global__ void k_attn2(const unsigned short* __restrict__ X2bf, const float* __restrict__ att_s,
                        const float* __restrict__ att_d, float* __restrict__ aS,
                        float* __restrict__ aD, int N) {
    int n = blockIdx.x * blockDim.x + threadIdx.x;
    if (n >= N) return;
    const unsigned* xr = (const unsigned*)(X2bf + (size_t)n * 40);
    float ss = 0.f, sd = 0.f;
#pragma unroll
    for (int j = 0; j < 20; j++) {
        unsigned p = xr[j];
        float x0 = bflo(p), x1 = bfhi(p);
        ss += x0 * att_s[2 * j] + x1 * att_s[2 * j + 1];
        sd += x0 * att_d[2 * j] + x1 * att_d[2 * j + 1];
    }
    aS[n] = ss;
    aD[n] = sd;
}

// ---------------- fused message + softmax-denominator ----------------
// Wave per destination node; lane holds 2 channels (bf16x2). Fused bias+ReLU.
__global__ __launch_bounds__(256) void k_msg1(const int* __restrict__ offsets,
                                              const int* __restrict__ csr_src,
                                              const float* __restrict__ aS,
                                              const float* __restrict__ aD,
                                              const unsigned short* __restrict__ Abf,
                                              const float* __restrict__ b1,
                                              float* __restrict__ H, int N) {
    int n = blockIdx.x * 4 + (threadIdx.x >> 6);
    if (n >= N) return;
    int lane = threadIdx.x & 63;
    int c0 = lane * 2;
    int h = lane >> 4;
    float adh = aD[n * 4 + h];
    float wself = __expf(lrelu(aS[n * 4 + h] + adh));
    unsigned ps = *(const unsigned*)(Abf + (size_t)n * 128 + c0);
    float acc0 = wself * bflo(ps), acc1 = wself * bfhi(ps);
    float wsum = wself;
    int b = offsets[n], e = offsets[n + 1];
    int i = b;
    for (; i + 2 <= e; i += 2) {
        int s0 = csr_src[i], s1 = csr_src[i + 1];
        unsigned p0 = *(const unsigned*)(Abf + (size_t)s0 * 128 + c0);
        unsigned p1 = *(const unsigned*)(Abf + (size_t)s1 * 128 + c0);
        float w0 = __expf(lrelu(aS[s0 * 4 + h] + adh));
        float w1 = __expf(lrelu(aS[s1 * 4 + h] + adh));
        acc0 += w0 * bflo(p0) + w1 * bflo(p1);
        acc1 += w0 * bfhi(p0) + w1 * bfhi(p1);
        wsum += w0 + w1;
    }
    if (i < e) {
        int s0 = csr_src[i];
        unsigned p0 = *(const unsigned*)(Abf + (size_t)s0 * 128 + c0);
        float w0 = __expf(lrelu(aS[s0 * 4 + h] + adh));
        acc0 += w0 * bflo(p0);
        acc1 += w0 * bfhi(p0);
        wsum += w0;
    }
    float inv = 1.0f / wsum;
    float2 bb = *(const float2*)(b1 + c0);
    float2 r;
    r.x = fmaxf(acc0 * inv + bb.x, 0.f);
    r.y = fmaxf(acc1 * inv + bb.y, 0.f);
    *(float2*)(H + (size_t)n * 128 + c0) = r;
}

// Wave per node, lanes 0..19 hold bf16x2 (40 ch). Fused bias.
__global__ __launch_bounds__(256) void k_msg2(const int* __restrict__ offsets,
                                              const int* __restrict__ csr_src,
                                              const float* __restrict__ aS,
                                              const float* __restrict__ aD,
                                              const unsigned short* __restrict__ X2bf,
                                              const float* __restrict__ b2,
                                              float* __restrict__ OUT, int N) {
    int n = blockIdx.x * 4 + (threadIdx.x >> 6);
    int lane = threadIdx.x & 63;
    if (n >= N || lane >= 20) return;
    int c0 = lane * 2;
    float adh = aD[n];
    float wself = __expf(lrelu(aS[n] + adh));
    unsigned ps = *(const unsigned*)(X2bf + (size_t)n * 40 + c0);
    float acc0 = wself * bflo(ps), acc1 = wself * bfhi(ps);
    float wsum = wself;
    int b = offsets[n], e = offsets[n + 1];
    int i = b;
    for (; i + 2 <= e; i += 2) {
        int s0 = csr_src[i], s1 = csr_src[i + 1];
        unsigned p0 = *(const unsigned*)(X2bf + (size_t)s0 * 40 + c0);
        unsigned p1 = *(const unsigned*)(X2bf + (size_t)s1 * 40 + c0);
        float w0 = __expf(lrelu(aS[s0] + adh));
        float w1 = __expf(lrelu(aS[s1] + adh));
        acc0 += w0 * bflo(p0) + w1 * bflo(p1);
        acc1 += w0 * bfhi(p0) + w1 * bfhi(p1);
        wsum += w0 + w1;
    }
    if (i < e) {
        int s0 = csr_src[i];
        unsigned p0 = *(const unsigned*)(X2bf + (size_t)s0 * 40 + c0);
        float w0 = __expf(lrelu(aS[s0] + adh));
        acc0 += w0 * bflo(p0);
        acc1 += w0 * bfhi(p0);
        wsum += w0;
    }
    float inv = 1.0f / wsum;
    OUT[(size_t)n * 40 + c0]     = acc0 * inv + b2[c0];
    OUT[(size_t)n * 40 + c0 + 1] = acc1 * inv + b2[c0 + 1];
}

extern "C" void kernel_launch(void* const* d_in, const int* in_sizes, int n_in,
                              void* d_out, int out_size, void* d_ws, size_t ws_size,
                              hipStream_t stream) {
    const float* x   = (const float*)d_in[0];
    const void*  ei  = d_in[1];
    const float* W1  = (const float*)d_in[2];
    const float* as1 = (const float*)d_in[3];
    const float* ad1 = (const float*)d_in[4];
    const float* b1  = (const float*)d_in[5];
    const float* W2  = (const float*)d_in[6];
    const float* as2 = (const float*)d_in[7];
    const float* ad2 = (const float*)d_in[8];
    const float* b2  = (const float*)d_in[9];
    float* out = (float*)d_out;

    const int N = in_sizes[0] / 128;
    const int E = in_sizes[1] / 2;

    // workspace layout
    char* w = (char*)d_ws;
    int* flag      = (int*)w;                 w += 16;
    int* offsets   = (int*)w;                 w += (size_t)(N + 1) * 4;
    int* cursor    = (int*)w;                 w += (size_t)N * 4;        // deg, then cursor
    int* csr_src   = (int*)w;                 w += (size_t)E * 4;
    float* aS1     = (float*)w;               w += (size_t)N * 4 * 4;
    float* aD1     = (float*)w;               w += (size_t)N * 4 * 4;
    float* aS2     = (float*)w;               w += (size_t)N * 4;
    float* aD2     = (float*)w;               w += (size_t)N * 4;
    unsigned short* Abf  = (unsigned short*)w; w += (size_t)N * 128 * 2; // xw1 bf16
    unsigned short* X2bf = (unsigned short*)w; w += (size_t)N * 40 * 2;  // xw2 bf16
    float* H       = (float*)w;               // [N,128] fp32

    k_detect<<<1, 256, 0, stream>>>((const int*)ei, 1024, flag);

    // CSR build (shared by both layers)
    hipMemsetAsync(cursor, 0, (size_t)N * 4, stream);
    k_degree<<<(E + 255) / 256, 256, 0, stream>>>(ei, flag, cursor, E);
    k_scan<<<1, 1024, 0, stream>>>(cursor, offsets, N);
    k_copy<<<(N + 255) / 256, 256, 0, stream>>>(offsets, cursor, N);
    k_scatter<<<(E + 255) / 256, 256, 0, stream>>>(ei, flag, cursor, csr_src, E);

    // layer 1
    const int gb = (N + 63) / 64;
    k_gemm1<<<gb, 256, 0, stream>>>(x, W1, Abf, N);
    k_attn1<<<(N * 4 + 255) / 256, 256, 0, stream>>>(Abf, as1, ad1, aS1, aD1, N);
    k_msg1<<<(N + 3) / 4, 256, 0, stream>>>(offsets, csr_src, aS1, aD1, Abf, b1, H, N);

    // layer 2
    k_gemm2<<<gb, 256, 0, stream>>>(H, W2, X2bf, N);
    k_attn2<<<(N + 255) / 256, 256, 0, stream>>>(X2bf, as2, ad2, aS2, aD2, N);
    k_msg2<<<(N + 3) / 4, 256, 0, stream>>>(offsets, csr_src, aS2, aD2, X2bf, b2, out, N);
}

// Round 5
// 576.002 us; speedup vs baseline: 24.7789x; 1.1691x over previous
//
#include <hip/hip_runtime.h>
#include <hip/hip_bf16.h>

#define NEG_SLOPE 0.2f

typedef _Float16 f16;
typedef f16 f16x8 __attribute__((ext_vector_type(8)));
typedef float f32x4 __attribute__((ext_vector_type(4)));

__device__ __forceinline__ float lrelu(float v) { return v > 0.f ? v : NEG_SLOPE * v; }

__device__ __forceinline__ unsigned pack_h2(float a, float b) {
    union { f16 h[2]; unsigned u; } c;
    c.h[0] = (f16)a; c.h[1] = (f16)b;
    return c.u;
}
__device__ __forceinline__ float2 unpack_h2(unsigned u) {
    union { unsigned u; f16 h[2]; } c;
    c.u = u;
    return make_float2((float)c.h[0], (float)c.h[1]);
}

// Detect whether edge_index arrived as int64 (odd 32-bit words all zero) or int32.
__global__ void k_detect(const int* __restrict__ ei32, int npairs, int* flag) {
    __shared__ int found;
    if (threadIdx.x == 0) found = 0;
    __syncthreads();
    for (int i = threadIdx.x; i < npairs; i += blockDim.x) {
        if (ei32[2 * i + 1] != 0) found = 1;
    }
    __syncthreads();
    if (threadIdx.x == 0) *flag = found ? 0 : 1;   // 1 => int64
}

__device__ __forceinline__ void load_edge(const void* ei, int f64, int e, int E, int& s, int& d) {
    if (f64) {
        const long long* p = (const long long*)ei;
        s = (int)p[e];
        d = (int)p[(long long)E + e];
    } else {
        const int* p = (const int*)ei;
        s = p[e];
        d = p[E + e];
    }
}

// ---------------- CSR build ----------------
__global__ void k_degree(const void* __restrict__ ei, const int* __restrict__ flag,
                         int* __restrict__ deg, int E) {
    int e = blockIdx.x * blockDim.x + threadIdx.x;
    if (e >= E) return;
    int s, d;
    load_edge(ei, *flag, e, E, s, d);
    atomicAdd(&deg[d], 1);
}

// Per-block scan: 1024 threads x 4 elems = 4096/block. Writes within-block
// prefix to offsets[idx+1] and block total to blksum.
__global__ __launch_bounds__(1024) void k_scan_blk(const int* __restrict__ deg,
                                                   int* __restrict__ offsets,
                                                   int* __restrict__ blksum, int N) {
    __shared__ int wsums[16];
    const int t = threadIdx.x;
    const int lane = t & 63;
    const int wid = t >> 6;
    int idx = blockIdx.x * 4096 + t * 4;
    int v0 = (idx + 0 < N) ? deg[idx + 0] : 0;
    int v1 = (idx + 1 < N) ? deg[idx + 1] : 0;
    int v2 = (idx + 2 < N) ? deg[idx + 2] : 0;
    int v3 = (idx + 3 < N) ? deg[idx + 3] : 0;
    int s1 = v0 + v1, s2 = s1 + v2, s3 = s2 + v3;
    int inc = s3;
#pragma unroll
    for (int off = 1; off < 64; off <<= 1) {
        int y = __shfl_up(inc, off);
        if (lane >= off) inc += y;
    }
    if (lane == 63) wsums[wid] = inc;
    __syncthreads();
    if (wid == 0) {
        int v = (lane < 16) ? wsums[lane] : 0;
        int wi = v;
#pragma unroll
        for (int off = 1; off < 16; off <<= 1) {
            int y = __shfl_up(wi, off);
            if (lane >= off) wi += y;
        }
        if (lane < 16) wsums[lane] = wi - v;      // exclusive
        if (lane == 15) blksum[blockIdx.x] = wi;  // block total
    }
    __syncthreads();
    int excl = wsums[wid] + (inc - s3);
    if (idx + 0 < N) offsets[idx + 1] = excl + v0;
    if (idx + 1 < N) offsets[idx + 2] = excl + s1;
    if (idx + 2 < N) offsets[idx + 3] = excl + s2;
    if (idx + 3 < N) offsets[idx + 4] = excl + s3;
}

__global__ void k_scan_top(const int* __restrict__ blksum, int* __restrict__ blkoff, int G) {
    int l = threadIdx.x;
    int v = (l < G) ? blksum[l] : 0;
    int inc = v;
#pragma unroll
    for (int off = 1; off < 64; off <<= 1) {
        int y = __shfl_up(inc, off);
        if (l >= off) inc += y;
    }
    if (l < G) blkoff[l] = inc - v;   // exclusive
}

__global__ void k_scan_add(int* __restrict__ offsets, const int* __restrict__ blkoff,
                           int* __restrict__ cursor, int N) {
    int n = blockIdx.x * blockDim.x + threadIdx.x;
    if (n >= N) return;
    int v = offsets[n + 1] + blkoff[n >> 12];
    offsets[n + 1] = v;
    if (n + 1 < N) cursor[n + 1] = v;
    if (n == 0) { offsets[0] = 0; cursor[0] = 0; }
}

__global__ void k_scatter(const void* __restrict__ ei, const int* __restrict__ flag,
                          int* __restrict__ cursor, int* __restrict__ csr_src, int E) {
    int e = blockIdx.x * blockDim.x + threadIdx.x;
    if (e >= E) return;
    int s, d;
    load_edge(ei, *flag, e, E, s, d);
    int slot = atomicAdd(&cursor[d], 1);
    csr_src[slot] = s;
}

// ---------------- weight prep: transposed f16 copies ----------------
__global__ void k_prep(const float* __restrict__ W1, const float* __restrict__ W2,
                       f16* __restrict__ W1t, f16* __restrict__ W2t) {
    int o = blockIdx.x * 256 + threadIdx.x;
    if (o < 128 * 128) {
        int n = o >> 7, k = o & 127;
        W1t[o] = (f16)W1[k * 128 + n];
    } else {
        int o2 = o - 128 * 128;
        if (o2 < 48 * 128) {
            int n = o2 >> 7, k = o2 & 127;
            W2t[o2] = (f16)(n < 40 ? W2[k * 40 + n] : 0.f);
        }
    }
}

// ---------------- GEMM1 (MFMA f16): Af = (f16)(X @ W1), [N][128] ----------------
__global__ __launch_bounds__(256) void k_gemm1(const float* __restrict__ X,
                                               const f16* __restrict__ W1t,
                                               f16* __restrict__ Af, int N) {
    __shared__ f16 sA[64 * 136];
    __shared__ f16 sB[128 * 136];
    const int t = threadIdx.x;
    const int row0 = blockIdx.x * 64;

    // stage X tile (fp32 -> f16)
    {
        int r = t >> 2, seg = t & 3;
        int row = row0 + r;
        if (row >= N) row = N - 1;
        const float4* xg = (const float4*)(X + (size_t)row * 128 + seg * 32);
        unsigned tmp[16];
#pragma unroll
        for (int j = 0; j < 8; j++) {
            float4 v = xg[j];
            tmp[2 * j]     = pack_h2(v.x, v.y);
            tmp[2 * j + 1] = pack_h2(v.z, v.w);
        }
        uint4* dst = (uint4*)&sA[r * 136 + seg * 32];
#pragma unroll
        for (int j = 0; j < 4; j++) dst[j] = ((uint4*)tmp)[j];
        // stage W1t (n-major): thread handles row n=t>>1, 64-half half-row.
        // R4 BUG was here: wrote only 4 uint4 (32 halfs) of the 64-half
        // half-row, leaving k in [32,64)+[96,128) as stale LDS. Now 8 uint4.
        int n = t >> 1, half = (t & 1) * 64;
        const uint4* src = (const uint4*)(W1t + n * 128 + half);
        uint4* dw = (uint4*)&sB[n * 136 + half];
#pragma unroll
        for (int j = 0; j < 8; j++) dw[j] = src[j];
    }
    __syncthreads();

    const int w = t >> 6, lane = t & 63, ln = lane & 15, q = lane >> 4;
    f32x4 acc[8];
#pragma unroll
    for (int c = 0; c < 8; c++) acc[c] = (f32x4){0.f, 0.f, 0.f, 0.f};

#pragma unroll
    for (int ks = 0; ks < 4; ks++) {
        f16x8 a = *(const f16x8*)&sA[(w * 16 + ln) * 136 + ks * 32 + q * 8];
#pragma unroll
        for (int c = 0; c < 8; c++) {
            f16x8 b = *(const f16x8*)&sB[(c * 16 + ln) * 136 + ks * 32 + q * 8];
            acc[c] = __builtin_amdgcn_mfma_f32_16x16x32_f16(a, b, acc[c], 0, 0, 0);
        }
    }

#pragma unroll
    for (int c = 0; c < 8; c++)
#pragma unroll
        for (int reg = 0; reg < 4; reg++) {
            int rg = row0 + w * 16 + q * 4 + reg;
            if (rg < N) Af[(size_t)rg * 128 + c * 16 + ln] = (f16)acc[c][reg];
        }
}

// ---------------- GEMM2 (MFMA f16): X2f = (f16)(Hf @ W2), [N][40] ----------------
__global__ __launch_bounds__(256) void k_gemm2(const f16* __restrict__ Hf,
                                               const f16* __restrict__ W2t,
                                               f16* __restrict__ X2f, int N) {
    __shared__ f16 sA[64 * 136];
    __shared__ f16 sB[48 * 136];
    const int t = threadIdx.x;
    const int row0 = blockIdx.x * 64;
    {
        int r = t >> 2, seg = t & 3;
        int row = row0 + r;
        if (row >= N) row = N - 1;
        const uint4* hg = (const uint4*)(Hf + (size_t)row * 128 + seg * 32);
        uint4* dst = (uint4*)&sA[r * 136 + seg * 32];
#pragma unroll
        for (int j = 0; j < 4; j++) dst[j] = hg[j];
        const uint4* wsrc = (const uint4*)W2t;
#pragma unroll
        for (int u = t; u < 768; u += 256) {   // 48*128 halfs = 768 uint4
            int o = u * 8;
            int n = o >> 7, ko = o & 127;
            *(uint4*)&sB[n * 136 + ko] = wsrc[u];
        }
    }
    __syncthreads();

    const int w = t >> 6, lane = t & 63, ln = lane & 15, q = lane >> 4;
    f32x4 acc[3];
#pragma unroll
    for (int c = 0; c < 3; c++) acc[c] = (f32x4){0.f, 0.f, 0.f, 0.f};

#pragma unroll
    for (int ks = 0; ks < 4; ks++) {
        f16x8 a = *(const f16x8*)&sA[(w * 16 + ln) * 136 + ks * 32 + q * 8];
#pragma unroll
        for (int c = 0; c < 3; c++) {
            f16x8 b = *(const f16x8*)&sB[(c * 16 + ln) * 136 + ks * 32 + q * 8];
            acc[c] = __builtin_amdgcn_mfma_f32_16x16x32_f16(a, b, acc[c], 0, 0, 0);
        }
    }

#pragma unroll
    for (int c = 0; c < 3; c++) {
        int col = c * 16 + ln;
        if (col < 40) {
#pragma unroll
            for (int reg = 0; reg < 4; reg++) {
                int rg = row0 + w * 16 + q * 4 + reg;
                if (rg < N) X2f[(size_t)rg * 40 + col] = (f16)acc[c][reg];
            }
        }
    }
}

// ---------------- attention dots (from f16) ----------------
__global__ void k_attn1(const f16* __restrict__ Af, const float* __restrict__ att_s,
                        const float* __restrict__ att_d, float* __restrict__ aS,
                        float* __restrict__ aD, int N) {
    int t = blockIdx.x * blockDim.x + threadIdx.x;
    if (t >= N * 4) return;
    int n = t >> 2, h = t & 3;
    const uint4* xr = (const uint4*)(Af + (size_t)n * 128 + h * 32);
    float ss = 0.f, sd = 0.f;
#pragma unroll
    for (int j = 0; j < 4; j++) {
        uint4 p = xr[j];
        float2 a0 = unpack_h2(p.x), a1 = unpack_h2(p.y), a2 = unpack_h2(p.z), a3 = unpack_h2(p.w);
        float xv[8] = {a0.x, a0.y, a1.x, a1.y, a2.x, a2.y, a3.x, a3.y};
        const float* as_ = att_s + h * 32 + j * 8;
        const float* ad_ = att_d + h * 32 + j * 8;
#pragma unroll
        for (int qq = 0; qq < 8; qq++) {
            ss += xv[qq] * as_[qq];
            sd += xv[qq] * ad_[qq];
        }
    }
    aS[t] = ss;
    aD[t] = sd;
}

__global__ void k_attn2(const f16* __restrict__ X2f, const float* __restrict__ att_s,
                        const float* __restrict__ att_d, float* __restrict__ aS,
                        float* __restrict__ aD, int N) {
    int n = blockIdx.x * blockDim.x + threadIdx.x;
    if (n >= N) return;
    const unsigned* xr = (const unsigned*)(X2f + (size_t)n * 40);
    float ss = 0.f, sd = 0.f;
#pragma unroll
    for (int j = 0; j < 20; j++) {
        float2 v = unpack_h2(xr[j]);
        ss += v.x * att_s[2 * j] + v.y * att_s[2 * j + 1];
        sd += v.x * att_d[2 * j] + v.y * att_d[2 * j + 1];
    }
    aS[n] = ss;
    aD[n] = sd;
}

// ---------------- alpha precompute ----------------
// wave per node; lane per edge; shuffle-reduce denominator; write normalized alphas.
__global__ __launch_bounds__(256) void k_alpha1(const int* __restrict__ offsets,
                                                const int* __restrict__ csr_src,
                                                const float* __restrict__ aS,
                                                const float* __restrict__ aD,
                                                float* __restrict__ alpha,
                                                float* __restrict__ selfA, int N) {
    int n = blockIdx.x * 4 + (threadIdx.x >> 6);
    if (n >= N) return;
    int lane = threadIdx.x & 63;
    float4 aDn = *(const float4*)(aD + (size_t)n * 4);
    float4 aSn = *(const float4*)(aS + (size_t)n * 4);
    float r0 = 0.f, r1 = 0.f, r2 = 0.f, r3 = 0.f;
    int b = offsets[n], e = offsets[n + 1];
    for (int i = b + lane; i < e; i += 64) {
        int s = csr_src[i];
        float4 v = *(const float4*)(aS + (size_t)s * 4);
        r0 += __expf(lrelu(v.x + aDn.x));
        r1 += __expf(lrelu(v.y + aDn.y));
        r2 += __expf(lrelu(v.z + aDn.z));
        r3 += __expf(lrelu(v.w + aDn.w));
    }
#pragma unroll
    for (int m = 1; m < 64; m <<= 1) {
        r0 += __shfl_xor(r0, m);
        r1 += __shfl_xor(r1, m);
        r2 += __shfl_xor(r2, m);
        r3 += __shfl_xor(r3, m);
    }
    float w0 = __expf(lrelu(aSn.x + aDn.x));
    float w1 = __expf(lrelu(aSn.y + aDn.y));
    float w2 = __expf(lrelu(aSn.z + aDn.z));
    float w3 = __expf(lrelu(aSn.w + aDn.w));
    float i0 = 1.f / (r0 + w0), i1 = 1.f / (r1 + w1), i2 = 1.f / (r2 + w2), i3 = 1.f / (r3 + w3);
    if (lane == 0)
        *(float4*)(selfA + (size_t)n * 4) = make_float4(w0 * i0, w1 * i1, w2 * i2, w3 * i3);
    for (int i = b + lane; i < e; i += 64) {
        int s = csr_src[i];
        float4 v = *(const float4*)(aS + (size_t)s * 4);
        float4 al;
        al.x = __expf(lrelu(v.x + aDn.x)) * i0;
        al.y = __expf(lrelu(v.y + aDn.y)) * i1;
        al.z = __expf(lrelu(v.z + aDn.z)) * i2;
        al.w = __expf(lrelu(v.w + aDn.w)) * i3;
        *(float4*)(alpha + (size_t)i * 4) = al;
    }
}

__global__ __launch_bounds__(256) void k_alpha2(const int* __restrict__ offsets,
                                                const int* __restrict__ csr_src,
                                                const float* __restrict__ aS,
                                                const float* __restrict__ aD,
                                                float* __restrict__ alpha,
                                                float* __restrict__ selfA, int N) {
    int n = blockIdx.x * 4 + (threadIdx.x >> 6);
    if (n >= N) return;
    int lane = threadIdx.x & 63;
    float aDn = aD[n];
    float r0 = 0.f;
    int b = offsets[n], e = offsets[n + 1];
    for (int i = b + lane; i < e; i += 64) {
        r0 += __expf(lrelu(aS[csr_src[i]] + aDn));
    }
#pragma unroll
    for (int m = 1; m < 64; m <<= 1) r0 += __shfl_xor(r0, m);
    float w0 = __expf(lrelu(aS[n] + aDn));
    float inv = 1.f / (r0 + w0);
    if (lane == 0) selfA[n] = w0 * inv;
    for (int i = b + lane; i < e; i += 64) {
        alpha[i] = __expf(lrelu(aS[csr_src[i]] + aDn)) * inv;
    }
}

// ---------------- message gather (pure FMA) ----------------
// wave per node; lane = 2 channels. Hf output f16 with fused bias+ReLU.
__global__ __launch_bounds__(256) void k_msg1(const int* __restrict__ offsets,
                                              const int* __restrict__ csr_src,
                                              const float* __restrict__ alpha,
                                              const float* __restrict__ selfA,
                                              const f16* __restrict__ Af,
                                              const float* __restrict__ b1,
                                              f16* __restrict__ Hf, int N) {
    int n = blockIdx.x * 4 + (threadIdx.x >> 6);
    if (n >= N) return;
    int lane = threadIdx.x & 63;
    int c0 = lane * 2;
    int h = lane >> 4;
    float sa = selfA[n * 4 + h];
    float2 pv = unpack_h2(*(const unsigned*)(Af + (size_t)n * 128 + c0));
    float acc0 = sa * pv.x, acc1 = sa * pv.y;
    int b = offsets[n], e = offsets[n + 1];
    int i = b;
    for (; i + 2 <= e; i += 2) {
        int s0 = csr_src[i], s1 = csr_src[i + 1];
        float a0 = alpha[(size_t)i * 4 + h];
        float a1 = alpha[(size_t)(i + 1) * 4 + h];
        float2 f0 = unpack_h2(*(const unsigned*)(Af + (size_t)s0 * 128 + c0));
        float2 f1 = unpack_h2(*(const unsigned*)(Af + (size_t)s1 * 128 + c0));
        acc0 += a0 * f0.x + a1 * f1.x;
        acc1 += a0 * f0.y + a1 * f1.y;
    }
    if (i < e) {
        int s0 = csr_src[i];
        float a0 = alpha[(size_t)i * 4 + h];
        float2 f0 = unpack_h2(*(const unsigned*)(Af + (size_t)s0 * 128 + c0));
        acc0 += a0 * f0.x;
        acc1 += a0 * f0.y;
    }
    float2 bb = *(const float2*)(b1 + c0);
    *(unsigned*)(Hf + (size_t)n * 128 + c0) =
        pack_h2(fmaxf(acc0 + bb.x, 0.f), fmaxf(acc1 + bb.y, 0.f));
}

// 3 nodes per wave (20 lanes each), 12 nodes per 256-block. Fused bias; fp32 out.
__global__ __launch_bounds__(256) void k_msg2(const int* __restrict__ offsets,
                                              const int* __restrict__ csr_src,
                                              const float* __restrict__ alpha,
                                              const float* __restrict__ selfA,
                                              const f16* __restrict__ X2f,
                                              const float* __restrict__ b2,
                                              float* __restrict__ OUT, int N) {
    int wv = threadIdx.x >> 6, lane = threadIdx.x & 63;
    if (lane >= 60) return;
    int g = lane / 20;
    int li = lane - g * 20;
    int n = blockIdx.x * 12 + wv * 3 + g;
    if (n >= N) return;
    int c0 = li * 2;
    float sa = selfA[n];
    float2 pv = unpack_h2(*(const unsigned*)(X2f + (size_t)n * 40 + c0));
    float acc0 = sa * pv.x, acc1 = sa * pv.y;
    int b = offsets[n], e = offsets[n + 1];
    int i = b;
    for (; i + 2 <= e; i += 2) {
        int s0 = csr_src[i], s1 = csr_src[i + 1];
        float a0 = alpha[i], a1 = alpha[i + 1];
        float2 f0 = unpack_h2(*(const unsigned*)(X2f + (size_t)s0 * 40 + c0));
        float2 f1 = unpack_h2(*(const unsigned*)(X2f + (size_t)s1 * 40 + c0));
        acc0 += a0 * f0.x + a1 * f1.x;
        acc1 += a0 * f0.y + a1 * f1.y;
    }
    if (i < e) {
        int s0 = csr_src[i];
        float a0 = alpha[i];
        float2 f0 = unpack_h2(*(const unsigned*)(X2f + (size_t)s0 * 40 + c0));
        acc0 += a0 * f0.x;
        acc1 += a0 * f0.y;
    }
    float2 bb = *(const float2*)(b2 + c0);
    *(float2*)(OUT + (size_t)n * 40 + c0) = make_float2(acc0 + bb.x, acc1 + bb.y);
}

extern "C" void kernel_launch(void* const* d_in, const int* in_sizes, int n_in,
                              void* d_out, int out_size, void* d_ws, size_t ws_size,
                              hipStream_t stream) {
    const float* x   = (const float*)d_in[0];
    const void*  ei  = d_in[1];
    const float* W1  = (const float*)d_in[2];
    const float* as1 = (const float*)d_in[3];
    const float* ad1 = (const float*)d_in[4];
    const float* b1  = (const float*)d_in[5];
    const float* W2  = (const float*)d_in[6];
    const float* as2 = (const float*)d_in[7];
    const float* ad2 = (const float*)d_in[8];
    const float* b2  = (const float*)d_in[9];
    float* out = (float*)d_out;

    const int N = in_sizes[0] / 128;
    const int E = in_sizes[1] / 2;

    // workspace layout
    char* w = (char*)d_ws;
    int* flag      = (int*)w;                 w += 16;
    int* offsets   = (int*)w;                 w += (size_t)(N + 1) * 4;
    int* cursor    = (int*)w;                 w += (size_t)N * 4;       // deg, then cursor
    int* csr_src   = (int*)w;                 w += (size_t)E * 4;
    int* blksum    = (int*)w;                 w += 64 * 4;
    int* blkoff    = (int*)w;                 w += 64 * 4;
    float* aS1     = (float*)w;               w += (size_t)N * 4 * 4;
    float* aD1     = (float*)w;               w += (size_t)N * 4 * 4;
    float* aS2     = (float*)w;               w += (size_t)N * 4;
    float* aD2     = (float*)w;               w += (size_t)N * 4;
    float* alpha1  = (float*)w;               w += (size_t)E * 4 * 4;
    float* alpha2  = (float*)w;               w += (size_t)E * 4;
    float* selfA1  = (float*)w;               w += (size_t)N * 4 * 4;
    float* selfA2  = (float*)w;               w += (size_t)N * 4;
    f16* W1t       = (f16*)w;                 w += 128 * 128 * 2;
    f16* W2t       = (f16*)w;                 w += 48 * 128 * 2;
    f16* Af        = (f16*)w;                 w += (size_t)N * 128 * 2; // xw1 f16
    f16* X2f       = (f16*)w;                 w += (size_t)N * 40 * 2;  // xw2 f16
    f16* Hf        = (f16*)w;                 // [N][128] f16

    k_detect<<<1, 256, 0, stream>>>((const int*)ei, 1024, flag);
    k_prep<<<88, 256, 0, stream>>>(W1, W2, W1t, W2t);

    // CSR build (shared by both layers)
    hipMemsetAsync(cursor, 0, (size_t)N * 4, stream);
    k_degree<<<(E + 255) / 256, 256, 0, stream>>>(ei, flag, cursor, E);
    const int G = (N + 4095) / 4096;
    k_scan_blk<<<G, 1024, 0, stream>>>(cursor, offsets, blksum, N);
    k_scan_top<<<1, 64, 0, stream>>>(blksum, blkoff, G);
    k_scan_add<<<(N + 255) / 256, 256, 0, stream>>>(offsets, blkoff, cursor, N);
    k_scatter<<<(E + 255) / 256, 256, 0, stream>>>(ei, flag, cursor, csr_src, E);

    // layer 1
    const int gb = (N + 63) / 64;
    k_gemm1<<<gb, 256, 0, stream>>>(x, W1t, Af, N);
    k_attn1<<<(N * 4 + 255) / 256, 256, 0, stream>>>(Af, as1, ad1, aS1, aD1, N);
    k_alpha1<<<(N + 3) / 4, 256, 0, stream>>>(offsets, csr_src, aS1, aD1, alpha1, selfA1, N);
    k_msg1<<<(N + 3) / 4, 256, 0, stream>>>(offsets, csr_src, alpha1, selfA1, Af, b1, Hf, N);

    // layer 2
    k_gemm2<<<gb, 256, 0, stream>>>(Hf, W2t, X2f, N);
    k_attn2<<<(N + 255) / 256, 256, 0, stream>>>(X2f, as2, ad2, aS2, aD2, N);
    k_alpha2<<<(N + 3) / 4, 256, 0, stream>>>(offsets, csr_src, aS2, aD2, alpha2, selfA2, N);
    k_msg2<<<(N + 11) / 12, 256, 0, stream>>>(offsets, csr_src, alpha2, selfA2, X2f, b2, out, N);
}

// Round 6
// 498.055 us; speedup vs baseline: 28.6569x; 1.1565x over previous
//
#include <hip/hip_runtime.h>
#include <hip/hip_bf16.h>

#define NEG_SLOPE 0.2f

typedef _Float16 f16;
typedef f16 f16x8 __attribute__((ext_vector_type(8)));
typedef float f32x4 __attribute__((ext_vector_type(4)));

__device__ __forceinline__ float lrelu(float v) { return v > 0.f ? v : NEG_SLOPE * v; }

__device__ __forceinline__ unsigned pack_h2(float a, float b) {
    union { f16 h[2]; unsigned u; } c;
    c.h[0] = (f16)a; c.h[1] = (f16)b;
    return c.u;
}
__device__ __forceinline__ float2 unpack_h2(unsigned u) {
    union { unsigned u; f16 h[2]; } c;
    c.u = u;
    return make_float2((float)c.h[0], (float)c.h[1]);
}

// Detect whether edge_index arrived as int64 (odd 32-bit words all zero) or int32.
__global__ void k_detect(const int* __restrict__ ei32, int npairs, int* flag) {
    __shared__ int found;
    if (threadIdx.x == 0) found = 0;
    __syncthreads();
    for (int i = threadIdx.x; i < npairs; i += blockDim.x) {
        if (ei32[2 * i + 1] != 0) found = 1;
    }
    __syncthreads();
    if (threadIdx.x == 0) *flag = found ? 0 : 1;   // 1 => int64
}

__device__ __forceinline__ void load_edge(const void* ei, int f64, int e, int E, int& s, int& d) {
    if (f64) {
        const long long* p = (const long long*)ei;
        s = (int)p[e];
        d = (int)p[(long long)E + e];
    } else {
        const int* p = (const int*)ei;
        s = p[e];
        d = p[E + e];
    }
}

// ---------------- CSR build ----------------
// Degree + rank in one pass: the random atomic is paid once, here.
__global__ void k_degree(const void* __restrict__ ei, const int* __restrict__ flag,
                         int* __restrict__ deg, int* __restrict__ rank, int E) {
    int e = blockIdx.x * blockDim.x + threadIdx.x;
    if (e >= E) return;
    int s, d;
    load_edge(ei, *flag, e, E, s, d);
    rank[e] = atomicAdd(&deg[d], 1);
}

// Per-block scan: 1024 threads x 4 elems = 4096/block.
__global__ __launch_bounds__(1024) void k_scan_blk(const int* __restrict__ deg,
                                                   int* __restrict__ offsets,
                                                   int* __restrict__ blksum, int N) {
    __shared__ int wsums[16];
    const int t = threadIdx.x;
    const int lane = t & 63;
    const int wid = t >> 6;
    int idx = blockIdx.x * 4096 + t * 4;
    int v0 = (idx + 0 < N) ? deg[idx + 0] : 0;
    int v1 = (idx + 1 < N) ? deg[idx + 1] : 0;
    int v2 = (idx + 2 < N) ? deg[idx + 2] : 0;
    int v3 = (idx + 3 < N) ? deg[idx + 3] : 0;
    int s1 = v0 + v1, s2 = s1 + v2, s3 = s2 + v3;
    int inc = s3;
#pragma unroll
    for (int off = 1; off < 64; off <<= 1) {
        int y = __shfl_up(inc, off);
        if (lane >= off) inc += y;
    }
    if (lane == 63) wsums[wid] = inc;
    __syncthreads();
    if (wid == 0) {
        int v = (lane < 16) ? wsums[lane] : 0;
        int wi = v;
#pragma unroll
        for (int off = 1; off < 16; off <<= 1) {
            int y = __shfl_up(wi, off);
            if (lane >= off) wi += y;
        }
        if (lane < 16) wsums[lane] = wi - v;      // exclusive
        if (lane == 15) blksum[blockIdx.x] = wi;  // block total
    }
    __syncthreads();
    int excl = wsums[wid] + (inc - s3);
    if (idx + 0 < N) offsets[idx + 1] = excl + v0;
    if (idx + 1 < N) offsets[idx + 2] = excl + s1;
    if (idx + 2 < N) offsets[idx + 3] = excl + s2;
    if (idx + 3 < N) offsets[idx + 4] = excl + s3;
}

__global__ void k_scan_top(const int* __restrict__ blksum, int* __restrict__ blkoff, int G) {
    int l = threadIdx.x;
    int v = (l < G) ? blksum[l] : 0;
    int inc = v;
#pragma unroll
    for (int off = 1; off < 64; off <<= 1) {
        int y = __shfl_up(inc, off);
        if (l >= off) inc += y;
    }
    if (l < G) blkoff[l] = inc - v;   // exclusive
}

__global__ void k_scan_add(int* __restrict__ offsets, const int* __restrict__ blkoff, int N) {
    int n = blockIdx.x * blockDim.x + threadIdx.x;
    if (n >= N) return;
    offsets[n + 1] += blkoff[n >> 12];
    if (n == 0) offsets[0] = 0;
}

// No atomic: slot = offsets[d] + rank[e].
__global__ void k_scatter(const void* __restrict__ ei, const int* __restrict__ flag,
                          const int* __restrict__ offsets, const int* __restrict__ rank,
                          int* __restrict__ csr_src, int E) {
    int e = blockIdx.x * blockDim.x + threadIdx.x;
    if (e >= E) return;
    int s, d;
    load_edge(ei, *flag, e, E, s, d);
    csr_src[offsets[d] + rank[e]] = s;
}

// ---------------- weight prep: transposed f16 copies ----------------
__global__ void k_prep(const float* __restrict__ W1, const float* __restrict__ W2,
                       f16* __restrict__ W1t, f16* __restrict__ W2t) {
    int o = blockIdx.x * 256 + threadIdx.x;
    if (o < 128 * 128) {
        int n = o >> 7, k = o & 127;
        W1t[o] = (f16)W1[k * 128 + n];
    } else {
        int o2 = o - 128 * 128;
        if (o2 < 48 * 128) {
            int n = o2 >> 7, k = o2 & 127;
            W2t[o2] = (f16)(n < 40 ? W2[k * 40 + n] : 0.f);
        }
    }
}

// ---------------- GEMM1 (MFMA f16): Af = (f16)(X @ W1), [N][128] ----------------
__global__ __launch_bounds__(256) void k_gemm1(const float* __restrict__ X,
                                               const f16* __restrict__ W1t,
                                               f16* __restrict__ Af, int N) {
    __shared__ f16 sA[64 * 136];
    __shared__ f16 sB[128 * 136];
    const int t = threadIdx.x;
    const int row0 = blockIdx.x * 64;

    {
        int r = t >> 2, seg = t & 3;
        int row = row0 + r;
        if (row >= N) row = N - 1;
        const float4* xg = (const float4*)(X + (size_t)row * 128 + seg * 32);
        unsigned tmp[16];
#pragma unroll
        for (int j = 0; j < 8; j++) {
            float4 v = xg[j];
            tmp[2 * j]     = pack_h2(v.x, v.y);
            tmp[2 * j + 1] = pack_h2(v.z, v.w);
        }
        uint4* dst = (uint4*)&sA[r * 136 + seg * 32];
#pragma unroll
        for (int j = 0; j < 4; j++) dst[j] = ((uint4*)tmp)[j];
        // full 64-half half-row (8 uint4) — R4 bug was 4.
        int n = t >> 1, half = (t & 1) * 64;
        const uint4* src = (const uint4*)(W1t + n * 128 + half);
        uint4* dw = (uint4*)&sB[n * 136 + half];
#pragma unroll
        for (int j = 0; j < 8; j++) dw[j] = src[j];
    }
    __syncthreads();

    const int w = t >> 6, lane = t & 63, ln = lane & 15, q = lane >> 4;
    f32x4 acc[8];
#pragma unroll
    for (int c = 0; c < 8; c++) acc[c] = (f32x4){0.f, 0.f, 0.f, 0.f};

#pragma unroll
    for (int ks = 0; ks < 4; ks++) {
        f16x8 a = *(const f16x8*)&sA[(w * 16 + ln) * 136 + ks * 32 + q * 8];
#pragma unroll
        for (int c = 0; c < 8; c++) {
            f16x8 b = *(const f16x8*)&sB[(c * 16 + ln) * 136 + ks * 32 + q * 8];
            acc[c] = __builtin_amdgcn_mfma_f32_16x16x32_f16(a, b, acc[c], 0, 0, 0);
        }
    }

#pragma unroll
    for (int c = 0; c < 8; c++)
#pragma unroll
        for (int reg = 0; reg < 4; reg++) {
            int rg = row0 + w * 16 + q * 4 + reg;
            if (rg < N) Af[(size_t)rg * 128 + c * 16 + ln] = (f16)acc[c][reg];
        }
}

// ---------------- GEMM2 (MFMA f16): X2f = (f16)(Hf @ W2), [N][40] ----------------
__global__ __launch_bounds__(256) void k_gemm2(const f16* __restrict__ Hf,
                                               const f16* __restrict__ W2t,
                                               f16* __restrict__ X2f, int N) {
    __shared__ f16 sA[64 * 136];
    __shared__ f16 sB[48 * 136];
    const int t = threadIdx.x;
    const int row0 = blockIdx.x * 64;
    {
        int r = t >> 2, seg = t & 3;
        int row = row0 + r;
        if (row >= N) row = N - 1;
        const uint4* hg = (const uint4*)(Hf + (size_t)row * 128 + seg * 32);
        uint4* dst = (uint4*)&sA[r * 136 + seg * 32];
#pragma unroll
        for (int j = 0; j < 4; j++) dst[j] = hg[j];
        const uint4* wsrc = (const uint4*)W2t;
#pragma unroll
        for (int u = t; u < 768; u += 256) {
            int o = u * 8;
            int n = o >> 7, ko = o & 127;
            *(uint4*)&sB[n * 136 + ko] = wsrc[u];
        }
    }
    __syncthreads();

    const int w = t >> 6, lane = t & 63, ln = lane & 15, q = lane >> 4;
    f32x4 acc[3];
#pragma unroll
    for (int c = 0; c < 3; c++) acc[c] = (f32x4){0.f, 0.f, 0.f, 0.f};

#pragma unroll
    for (int ks = 0; ks < 4; ks++) {
        f16x8 a = *(const f16x8*)&sA[(w * 16 + ln) * 136 + ks * 32 + q * 8];
#pragma unroll
        for (int c = 0; c < 3; c++) {
            f16x8 b = *(const f16x8*)&sB[(c * 16 + ln) * 136 + ks * 32 + q * 8];
            acc[c] = __builtin_amdgcn_mfma_f32_16x16x32_f16(a, b, acc[c], 0, 0, 0);
        }
    }

#pragma unroll
    for (int c = 0; c < 3; c++) {
        int col = c * 16 + ln;
        if (col < 40) {
#pragma unroll
            for (int reg = 0; reg < 4; reg++) {
                int rg = row0 + w * 16 + q * 4 + reg;
                if (rg < N) X2f[(size_t)rg * 40 + col] = (f16)acc[c][reg];
            }
        }
    }
}

// ---------------- attention dots (from f16) ----------------
__global__ void k_attn1(const f16* __restrict__ Af, const float* __restrict__ att_s,
                        const float* __restrict__ att_d, float* __restrict__ aS,
                        float* __restrict__ aD, int N) {
    int t = blockIdx.x * blockDim.x + threadIdx.x;
    if (t >= N * 4) return;
    int n = t >> 2, h = t & 3;
    const uint4* xr = (const uint4*)(Af + (size_t)n * 128 + h * 32);
    float ss = 0.f, sd = 0.f;
#pragma unroll
    for (int j = 0; j < 4; j++) {
        uint4 p = xr[j];
        float2 a0 = unpack_h2(p.x), a1 = unpack_h2(p.y), a2 = unpack_h2(p.z), a3 = unpack_h2(p.w);
        float xv[8] = {a0.x, a0.y, a1.x, a1.y, a2.x, a2.y, a3.x, a3.y};
        const float* as_ = att_s + h * 32 + j * 8;
        const float* ad_ = att_d + h * 32 + j * 8;
#pragma unroll
        for (int qq = 0; qq < 8; qq++) {
            ss += xv[qq] * as_[qq];
            sd += xv[qq] * ad_[qq];
        }
    }
    aS[t] = ss;
    aD[t] = sd;
}

__global__ void k_attn2(const f16* __restrict__ X2f, const float* __restrict__ att_s,
                        const float* __restrict__ att_d, float* __restrict__ aS,
                        float* __restrict__ aD, int N) {
    int n = blockIdx.x * blockDim.x + threadIdx.x;
    if (n >= N) return;
    const unsigned* xr = (const unsigned*)(X2f + (size_t)n * 40);
    float ss = 0.f, sd = 0.f;
#pragma unroll
    for (int j = 0; j < 20; j++) {
        float2 v = unpack_h2(xr[j]);
        ss += v.x * att_s[2 * j] + v.y * att_s[2 * j + 1];
        sd += v.x * att_d[2 * j] + v.y * att_d[2 * j + 1];
    }
    aS[n] = ss;
    aD[n] = sd;
}

// ---------------- alpha precompute ----------------
// wave per node; alphas packed f16x4 per edge (2 words).
__global__ __launch_bounds__(256) void k_alpha1(const int* __restrict__ offsets,
                                                const int* __restrict__ csr_src,
                                                const float* __restrict__ aS,
                                                const float* __restrict__ aD,
                                                uint2* __restrict__ alpha8,
                                                float* __restrict__ selfA, int N) {
    int n = blockIdx.x * 4 + (threadIdx.x >> 6);
    if (n >= N) return;
    int lane = threadIdx.x & 63;
    float4 aDn = *(const float4*)(aD + (size_t)n * 4);
    float4 aSn = *(const float4*)(aS + (size_t)n * 4);
    float r0 = 0.f, r1 = 0.f, r2 = 0.f, r3 = 0.f;
    int b = offsets[n], e = offsets[n + 1];
    for (int i = b + lane; i < e; i += 64) {
        int s = csr_src[i];
        float4 v = *(const float4*)(aS + (size_t)s * 4);
        r0 += __expf(lrelu(v.x + aDn.x));
        r1 += __expf(lrelu(v.y + aDn.y));
        r2 += __expf(lrelu(v.z + aDn.z));
        r3 += __expf(lrelu(v.w + aDn.w));
    }
#pragma unroll
    for (int m = 1; m < 64; m <<= 1) {
        r0 += __shfl_xor(r0, m);
        r1 += __shfl_xor(r1, m);
        r2 += __shfl_xor(r2, m);
        r3 += __shfl_xor(r3, m);
    }
    float w0 = __expf(lrelu(aSn.x + aDn.x));
    float w1 = __expf(lrelu(aSn.y + aDn.y));
    float w2 = __expf(lrelu(aSn.z + aDn.z));
    float w3 = __expf(lrelu(aSn.w + aDn.w));
    float i0 = 1.f / (r0 + w0), i1 = 1.f / (r1 + w1), i2 = 1.f / (r2 + w2), i3 = 1.f / (r3 + w3);
    if (lane == 0)
        *(float4*)(selfA + (size_t)n * 4) = make_float4(w0 * i0, w1 * i1, w2 * i2, w3 * i3);
    for (int i = b + lane; i < e; i += 64) {
        int s = csr_src[i];
        float4 v = *(const float4*)(aS + (size_t)s * 4);
        float a0 = __expf(lrelu(v.x + aDn.x)) * i0;
        float a1 = __expf(lrelu(v.y + aDn.y)) * i1;
        float a2 = __expf(lrelu(v.z + aDn.z)) * i2;
        float a3 = __expf(lrelu(v.w + aDn.w)) * i3;
        alpha8[i] = make_uint2(pack_h2(a0, a1), pack_h2(a2, a3));
    }
}

__global__ __launch_bounds__(256) void k_alpha2(const int* __restrict__ offsets,
                                                const int* __restrict__ csr_src,
                                                const float* __restrict__ aS,
                                                const float* __restrict__ aD,
                                                float* __restrict__ alpha,
                                                float* __restrict__ selfA, int N) {
    int n = blockIdx.x * 4 + (threadIdx.x >> 6);
    if (n >= N) return;
    int lane = threadIdx.x & 63;
    float aDn = aD[n];
    float r0 = 0.f;
    int b = offsets[n], e = offsets[n + 1];
    for (int i = b + lane; i < e; i += 64) {
        r0 += __expf(lrelu(aS[csr_src[i]] + aDn));
    }
#pragma unroll
    for (int m = 1; m < 64; m <<= 1) r0 += __shfl_xor(r0, m);
    float w0 = __expf(lrelu(aS[n] + aDn));
    float inv = 1.f / (r0 + w0);
    if (lane == 0) selfA[n] = w0 * inv;
    for (int i = b + lane; i < e; i += 64) {
        alpha[i] = __expf(lrelu(aS[csr_src[i]] + aDn)) * inv;
    }
}

// ---------------- message gather (pure FMA) ----------------
// 2 waves per node (1 channel/lane); unroll-4 for MLP. Fused bias+ReLU, f16 out.
__global__ __launch_bounds__(256) void k_msg1(const int* __restrict__ offsets,
                                              const int* __restrict__ csr_src,
                                              const uint2* __restrict__ alpha8,
                                              const float* __restrict__ selfA,
                                              const f16* __restrict__ Af,
                                              const float* __restrict__ b1,
                                              f16* __restrict__ Hf, int N) {
    int wave = threadIdx.x >> 6;
    int lane = threadIdx.x & 63;
    int n = blockIdx.x * 2 + (wave >> 1);
    if (n >= N) return;
    int c = (wave & 1) * 64 + lane;   // channel 0..127
    int h = c >> 5;
    int word = h >> 1, sub = h & 1;   // uniform per wave
    float sa = selfA[n * 4 + h];
    float acc = sa * (float)Af[(size_t)n * 128 + c];
    int b = offsets[n], e = offsets[n + 1];
    int i = b;
    for (; i + 4 <= e; i += 4) {
        int s0 = csr_src[i], s1 = csr_src[i + 1], s2 = csr_src[i + 2], s3 = csr_src[i + 3];
        const unsigned* w0p = (const unsigned*)&alpha8[i];
        float2 u0 = unpack_h2(w0p[word]);
        float2 u1 = unpack_h2(w0p[2 + word]);
        float2 u2 = unpack_h2(w0p[4 + word]);
        float2 u3 = unpack_h2(w0p[6 + word]);
        float a0 = sub ? u0.y : u0.x;
        float a1 = sub ? u1.y : u1.x;
        float a2 = sub ? u2.y : u2.x;
        float a3 = sub ? u3.y : u3.x;
        float f0 = (float)Af[(size_t)s0 * 128 + c];
        float f1 = (float)Af[(size_t)s1 * 128 + c];
        float f2 = (float)Af[(size_t)s2 * 128 + c];
        float f3 = (float)Af[(size_t)s3 * 128 + c];
        acc += a0 * f0 + a1 * f1 + a2 * f2 + a3 * f3;
    }
    for (; i < e; i++) {
        int s0 = csr_src[i];
        float2 u0 = unpack_h2(((const unsigned*)&alpha8[i])[word]);
        float a0 = sub ? u0.y : u0.x;
        acc += a0 * (float)Af[(size_t)s0 * 128 + c];
    }
    Hf[(size_t)n * 128 + c] = (f16)fmaxf(acc + b1[c], 0.f);
}

// 3 nodes per wave (20 lanes each); unroll-4. Fused bias; fp32 out.
__global__ __launch_bounds__(256) void k_msg2(const int* __restrict__ offsets,
                                              const int* __restrict__ csr_src,
                                              const float* __restrict__ alpha,
                                              const float* __restrict__ selfA,
                                              const f16* __restrict__ X2f,
                                              const float* __restrict__ b2,
                                              float* __restrict__ OUT, int N) {
    int wv = threadIdx.x >> 6, lane = threadIdx.x & 63;
    if (lane >= 60) return;
    int g = lane / 20;
    int li = lane - g * 20;
    int n = blockIdx.x * 12 + wv * 3 + g;
    if (n >= N) return;
    int c0 = li * 2;
    float sa = selfA[n];
    float2 pv = unpack_h2(*(const unsigned*)(X2f + (size_t)n * 40 + c0));
    float acc0 = sa * pv.x, acc1 = sa * pv.y;
    int b = offsets[n], e = offsets[n + 1];
    int i = b;
    for (; i + 4 <= e; i += 4) {
        int s0 = csr_src[i], s1 = csr_src[i + 1], s2 = csr_src[i + 2], s3 = csr_src[i + 3];
        float a0 = alpha[i], a1 = alpha[i + 1], a2 = alpha[i + 2], a3 = alpha[i + 3];
        float2 f0 = unpack_h2(*(const unsigned*)(X2f + (size_t)s0 * 40 + c0));
        float2 f1 = unpack_h2(*(const unsigned*)(X2f + (size_t)s1 * 40 + c0));
        float2 f2 = unpack_h2(*(const unsigned*)(X2f + (size_t)s2 * 40 + c0));
        float2 f3 = unpack_h2(*(const unsigned*)(X2f + (size_t)s3 * 40 + c0));
        acc0 += a0 * f0.x + a1 * f1.x + a2 * f2.x + a3 * f3.x;
        acc1 += a0 * f0.y + a1 * f1.y + a2 * f2.y + a3 * f3.y;
    }
    for (; i < e; i++) {
        int s0 = csr_src[i];
        float a0 = alpha[i];
        float2 f0 = unpack_h2(*(const unsigned*)(X2f + (size_t)s0 * 40 + c0));
        acc0 += a0 * f0.x;
        acc1 += a0 * f0.y;
    }
    float2 bb = *(const float2*)(b2 + c0);
    *(float2*)(OUT + (size_t)n * 40 + c0) = make_float2(acc0 + bb.x, acc1 + bb.y);
}

extern "C" void kernel_launch(void* const* d_in, const int* in_sizes, int n_in,
                              void* d_out, int out_size, void* d_ws, size_t ws_size,
                              hipStream_t stream) {
    const float* x   = (const float*)d_in[0];
    const void*  ei  = d_in[1];
    const float* W1  = (const float*)d_in[2];
    const float* as1 = (const float*)d_in[3];
    const float* ad1 = (const float*)d_in[4];
    const float* b1  = (const float*)d_in[5];
    const float* W2  = (const float*)d_in[6];
    const float* as2 = (const float*)d_in[7];
    const float* ad2 = (const float*)d_in[8];
    const float* b2  = (const float*)d_in[9];
    float* out = (float*)d_out;

    const int N = in_sizes[0] / 128;
    const int E = in_sizes[1] / 2;

    // workspace layout
    char* w = (char*)d_ws;
    int* flag      = (int*)w;                 w += 16;
    int* offsets   = (int*)w;                 w += (size_t)(N + 1) * 4;
    int* deg       = (int*)w;                 w += (size_t)N * 4;
    int* rank      = (int*)w;                 w += (size_t)E * 4;
    int* csr_src   = (int*)w;                 w += (size_t)E * 4;
    int* blksum    = (int*)w;                 w += 64 * 4;
    int* blkoff    = (int*)w;                 w += 64 * 4;
    float* aS1     = (float*)w;               w += (size_t)N * 4 * 4;
    float* aD1     = (float*)w;               w += (size_t)N * 4 * 4;
    float* aS2     = (float*)w;               w += (size_t)N * 4;
    float* aD2     = (float*)w;               w += (size_t)N * 4;
    uint2* alpha8  = (uint2*)w;               w += (size_t)E * 8;       // f16x4/edge
    float* alpha2  = (float*)w;               w += (size_t)E * 4;
    float* selfA1  = (float*)w;               w += (size_t)N * 4 * 4;
    float* selfA2  = (float*)w;               w += (size_t)N * 4;
    f16* W1t       = (f16*)w;                 w += 128 * 128 * 2;
    f16* W2t       = (f16*)w;                 w += 48 * 128 * 2;
    f16* Af        = (f16*)w;                 w += (size_t)N * 128 * 2;
    f16* X2f       = (f16*)w;                 w += (size_t)N * 40 * 2;
    f16* Hf        = (f16*)w;                 // [N][128] f16

    k_detect<<<1, 256, 0, stream>>>((const int*)ei, 1024, flag);
    k_prep<<<88, 256, 0, stream>>>(W1, W2, W1t, W2t);

    // CSR build (shared by both layers)
    hipMemsetAsync(deg, 0, (size_t)N * 4, stream);
    k_degree<<<(E + 255) / 256, 256, 0, stream>>>(ei, flag, deg, rank, E);
    const int G = (N + 4095) / 4096;
    k_scan_blk<<<G, 1024, 0, stream>>>(deg, offsets, blksum, N);
    k_scan_top<<<1, 64, 0, stream>>>(blksum, blkoff, G);
    k_scan_add<<<(N + 255) / 256, 256, 0, stream>>>(offsets, blkoff, N);
    k_scatter<<<(E + 255) / 256, 256, 0, stream>>>(ei, flag, offsets, rank, csr_src, E);

    // layer 1
    const int gb = (N + 63) / 64;
    k_gemm1<<<gb, 256, 0, stream>>>(x, W1t, Af, N);
    k_attn1<<<(N * 4 + 255) / 256, 256, 0, stream>>>(Af, as1, ad1, aS1, aD1, N);
    k_alpha1<<<(N + 3) / 4, 256, 0, stream>>>(offsets, csr_src, aS1, aD1, alpha8, selfA1, N);
    k_msg1<<<(N + 1) / 2, 256, 0, stream>>>(offsets, csr_src, alpha8, selfA1, Af, b1, Hf, N);

    // layer 2
    k_gemm2<<<gb, 256, 0, stream>>>(Hf, W2t, X2f, N);
    k_attn2<<<(N + 255) / 256, 256, 0, stream>>>(X2f, as2, ad2, aS2, aD2, N);
    k_alpha2<<<(N + 3) / 4, 256, 0, stream>>>(offsets, csr_src, aS2, aD2, alpha2, selfA2, N);
    k_msg2<<<(N + 11) / 12, 256, 0, stream>>>(offsets, csr_src, alpha2, selfA2, X2f, b2, out, N);
}

// Round 9
// 448.775 us; speedup vs baseline: 31.8037x; 1.1098x over previous
//
#include <hip/hip_runtime.h>
#include <hip/hip_bf16.h>

#define NEG_SLOPE 0.2f

typedef _Float16 f16;
typedef f16 f16x8 __attribute__((ext_vector_type(8)));
typedef float f32x4 __attribute__((ext_vector_type(4)));

__device__ __forceinline__ float lrelu(float v) { return v > 0.f ? v : NEG_SLOPE * v; }

__device__ __forceinline__ unsigned pack_h2(float a, float b) {
    union { f16 h[2]; unsigned u; } c;
    c.h[0] = (f16)a; c.h[1] = (f16)b;
    return c.u;
}
__device__ __forceinline__ float2 unpack_h2(unsigned u) {
    union { unsigned u; f16 h[2]; } c;
    c.u = u;
    return make_float2((float)c.h[0], (float)c.h[1]);
}

// Detect whether edge_index arrived as int64 (odd 32-bit words all zero) or int32.
__global__ void k_detect(const int* __restrict__ ei32, int npairs, int* flag) {
    __shared__ int found;
    if (threadIdx.x == 0) found = 0;
    __syncthreads();
    for (int i = threadIdx.x; i < npairs; i += blockDim.x) {
        if (ei32[2 * i + 1] != 0) found = 1;
    }
    __syncthreads();
    if (threadIdx.x == 0) *flag = found ? 0 : 1;   // 1 => int64
}

__device__ __forceinline__ void load_edge(const void* ei, int f64, int e, int E, int& s, int& d) {
    if (f64) {
        const long long* p = (const long long*)ei;
        s = (int)p[e];
        d = (int)p[(long long)E + e];
    } else {
        const int* p = (const int*)ei;
        s = p[e];
        d = p[E + e];
    }
}

// ---------------- CSR build ----------------
__global__ void k_degree(const void* __restrict__ ei, const int* __restrict__ flag,
                         int* __restrict__ deg, int* __restrict__ rank, int E) {
    int e = blockIdx.x * blockDim.x + threadIdx.x;
    if (e >= E) return;
    int s, d;
    load_edge(ei, *flag, e, E, s, d);
    rank[e] = atomicAdd(&deg[d], 1);
}

__global__ __launch_bounds__(1024) void k_scan_blk(const int* __restrict__ deg,
                                                   int* __restrict__ offsets,
                                                   int* __restrict__ blksum, int N) {
    __shared__ int wsums[16];
    const int t = threadIdx.x;
    const int lane = t & 63;
    const int wid = t >> 6;
    int idx = blockIdx.x * 4096 + t * 4;
    int v0 = (idx + 0 < N) ? deg[idx + 0] : 0;
    int v1 = (idx + 1 < N) ? deg[idx + 1] : 0;
    int v2 = (idx + 2 < N) ? deg[idx + 2] : 0;
    int v3 = (idx + 3 < N) ? deg[idx + 3] : 0;
    int s1 = v0 + v1, s2 = s1 + v2, s3 = s2 + v3;
    int inc = s3;
#pragma unroll
    for (int off = 1; off < 64; off <<= 1) {
        int y = __shfl_up(inc, off);
        if (lane >= off) inc += y;
    }
    if (lane == 63) wsums[wid] = inc;
    __syncthreads();
    if (wid == 0) {
        int v = (lane < 16) ? wsums[lane] : 0;
        int wi = v;
#pragma unroll
        for (int off = 1; off < 16; off <<= 1) {
            int y = __shfl_up(wi, off);
            if (lane >= off) wi += y;
        }
        if (lane < 16) wsums[lane] = wi - v;
        if (lane == 15) blksum[blockIdx.x] = wi;
    }
    __syncthreads();
    int excl = wsums[wid] + (inc - s3);
    if (idx + 0 < N) offsets[idx + 1] = excl + v0;
    if (idx + 1 < N) offsets[idx + 2] = excl + s1;
    if (idx + 2 < N) offsets[idx + 3] = excl + s2;
    if (idx + 3 < N) offsets[idx + 4] = excl + s3;
}

__global__ void k_scan_top(const int* __restrict__ blksum, int* __restrict__ blkoff, int G) {
    int l = threadIdx.x;
    int v = (l < G) ? blksum[l] : 0;
    int inc = v;
#pragma unroll
    for (int off = 1; off < 64; off <<= 1) {
        int y = __shfl_up(inc, off);
        if (l >= off) inc += y;
    }
    if (l < G) blkoff[l] = inc - v;
}

__global__ void k_scan_add(int* __restrict__ offsets, const int* __restrict__ blkoff, int N) {
    int n = blockIdx.x * blockDim.x + threadIdx.x;
    if (n >= N) return;
    offsets[n + 1] += blkoff[n >> 12];
    if (n == 0) offsets[0] = 0;
}

__global__ void k_scatter(const void* __restrict__ ei, const int* __restrict__ flag,
                          const int* __restrict__ offsets, const int* __restrict__ rank,
                          int* __restrict__ csr_src, int E) {
    int e = blockIdx.x * blockDim.x + threadIdx.x;
    if (e >= E) return;
    int s, d;
    load_edge(ei, *flag, e, E, s, d);
    csr_src[offsets[d] + rank[e]] = s;
}

// ---------------- weight prep: transposed f16 copies ----------------
__global__ void k_prep(const float* __restrict__ W1, const float* __restrict__ W2,
                       f16* __restrict__ W1t, f16* __restrict__ W2t) {
    int o = blockIdx.x * 256 + threadIdx.x;
    if (o < 128 * 128) {
        int n = o >> 7, k = o & 127;
        W1t[o] = (f16)W1[k * 128 + n];
    } else {
        int o2 = o - 128 * 128;
        if (o2 < 48 * 128) {
            int n = o2 >> 7, k = o2 & 127;
            W2t[o2] = (f16)(n < 40 ? W2[k * 40 + n] : 0.f);
        }
    }
}

// ---------------- GEMM1 (MFMA f16): Af = (f16)(X @ W1), [N][128] ----------------
__global__ __launch_bounds__(256) void k_gemm1(const float* __restrict__ X,
                                               const f16* __restrict__ W1t,
                                               f16* __restrict__ Af, int N) {
    __shared__ f16 sA[64 * 136];
    __shared__ f16 sB[128 * 136];
    const int t = threadIdx.x;
    const int row0 = blockIdx.x * 64;

    {
        int r = t >> 2, seg = t & 3;
        int row = row0 + r;
        if (row >= N) row = N - 1;
        const float4* xg = (const float4*)(X + (size_t)row * 128 + seg * 32);
        unsigned tmp[16];
#pragma unroll
        for (int j = 0; j < 8; j++) {
            float4 v = xg[j];
            tmp[2 * j]     = pack_h2(v.x, v.y);
            tmp[2 * j + 1] = pack_h2(v.z, v.w);
        }
        uint4* dst = (uint4*)&sA[r * 136 + seg * 32];
#pragma unroll
        for (int j = 0; j < 4; j++) dst[j] = ((uint4*)tmp)[j];
        int n = t >> 1, half = (t & 1) * 64;
        const uint4* src = (const uint4*)(W1t + n * 128 + half);
        uint4* dw = (uint4*)&sB[n * 136 + half];
#pragma unroll
        for (int j = 0; j < 8; j++) dw[j] = src[j];
    }
    __syncthreads();

    const int w = t >> 6, lane = t & 63, ln = lane & 15, q = lane >> 4;
    f32x4 acc[8];
#pragma unroll
    for (int c = 0; c < 8; c++) acc[c] = (f32x4){0.f, 0.f, 0.f, 0.f};

#pragma unroll
    for (int ks = 0; ks < 4; ks++) {
        f16x8 a = *(const f16x8*)&sA[(w * 16 + ln) * 136 + ks * 32 + q * 8];
#pragma unroll
        for (int c = 0; c < 8; c++) {
            f16x8 b = *(const f16x8*)&sB[(c * 16 + ln) * 136 + ks * 32 + q * 8];
            acc[c] = __builtin_amdgcn_mfma_f32_16x16x32_f16(a, b, acc[c], 0, 0, 0);
        }
    }

#pragma unroll
    for (int c = 0; c < 8; c++)
#pragma unroll
        for (int reg = 0; reg < 4; reg++) {
            int rg = row0 + w * 16 + q * 4 + reg;
            if (rg < N) Af[(size_t)rg * 128 + c * 16 + ln] = (f16)acc[c][reg];
        }
}

// ---------------- GEMM2 (MFMA f16): X2f = (f16)(Hf @ W2), [N][40] ----------------
__global__ __launch_bounds__(256) void k_gemm2(const f16* __restrict__ Hf,
                                               const f16* __restrict__ W2t,
                                               f16* __restrict__ X2f, int N) {
    __shared__ f16 sA[64 * 136];
    __shared__ f16 sB[48 * 136];
    const int t = threadIdx.x;
    const int row0 = blockIdx.x * 64;
    {
        int r = t >> 2, seg = t & 3;
        int row = row0 + r;
        if (row >= N) row = N - 1;
        const uint4* hg = (const uint4*)(Hf + (size_t)row * 128 + seg * 32);
        uint4* dst = (uint4*)&sA[r * 136 + seg * 32];
#pragma unroll
        for (int j = 0; j < 4; j++) dst[j] = hg[j];
        const uint4* wsrc = (const uint4*)W2t;
#pragma unroll
        for (int u = t; u < 768; u += 256) {
            int o = u * 8;
            int n = o >> 7, ko = o & 127;
            *(uint4*)&sB[n * 136 + ko] = wsrc[u];
        }
    }
    __syncthreads();

    const int w = t >> 6, lane = t & 63, ln = lane & 15, q = lane >> 4;
    f32x4 acc[3];
#pragma unroll
    for (int c = 0; c < 3; c++) acc[c] = (f32x4){0.f, 0.f, 0.f, 0.f};

#pragma unroll
    for (int ks = 0; ks < 4; ks++) {
        f16x8 a = *(const f16x8*)&sA[(w * 16 + ln) * 136 + ks * 32 + q * 8];
#pragma unroll
        for (int c = 0; c < 3; c++) {
            f16x8 b = *(const f16x8*)&sB[(c * 16 + ln) * 136 + ks * 32 + q * 8];
            acc[c] = __builtin_amdgcn_mfma_f32_16x16x32_f16(a, b, acc[c], 0, 0, 0);
        }
    }

#pragma unroll
    for (int c = 0; c < 3; c++) {
        int col = c * 16 + ln;
        if (col < 40) {
#pragma unroll
            for (int reg = 0; reg < 4; reg++) {
                int rg = row0 + w * 16 + q * 4 + reg;
                if (rg < N) X2f[(size_t)rg * 40 + col] = (f16)acc[c][reg];
            }
        }
    }
}

// ---------------- attention dots (from f16) ----------------
__global__ void k_attn1(const f16* __restrict__ Af, const float* __restrict__ att_s,
                        const float* __restrict__ att_d, float* __restrict__ aS,
                        float* __restrict__ aD, int N) {
    int t = blockIdx.x * blockDim.x + threadIdx.x;
    if (t >= N * 4) return;
    int n = t >> 2, h = t & 3;
    const uint4* xr = (const uint4*)(Af + (size_t)n * 128 + h * 32);
    float ss = 0.f, sd = 0.f;
#pragma unroll
    for (int j = 0; j < 4; j++) {
        uint4 p = xr[j];
        float2 a0 = unpack_h2(p.x), a1 = unpack_h2(p.y), a2 = unpack_h2(p.z), a3 = unpack_h2(p.w);
        float xv[8] = {a0.x, a0.y, a1.x, a1.y, a2.x, a2.y, a3.x, a3.y};
        const float* as_ = att_s + h * 32 + j * 8;
        const float* ad_ = att_d + h * 32 + j * 8;
#pragma unroll
        for (int qq = 0; qq < 8; qq++) {
            ss += xv[qq] * as_[qq];
            sd += xv[qq] * ad_[qq];
        }
    }
    aS[t] = ss;
    aD[t] = sd;
}

__global__ void k_attn2(const f16* __restrict__ X2f, const float* __restrict__ att_s,
                        const float* __restrict__ att_d, float* __restrict__ aS,
                        float* __restrict__ aD, int N) {
    int n = blockIdx.x * blockDim.x + threadIdx.x;
    if (n >= N) return;
    const unsigned* xr = (const unsigned*)(X2f + (size_t)n * 40);
    float ss = 0.f, sd = 0.f;
#pragma unroll
    for (int j = 0; j < 20; j++) {
        float2 v = unpack_h2(xr[j]);
        ss += v.x * att_s[2 * j] + v.y * att_s[2 * j + 1];
        sd += v.x * att_d[2 * j] + v.y * att_d[2 * j + 1];
    }
    aS[n] = ss;
    aD[n] = sd;
}

// ---------------- alpha precompute (R6-proven 64-lane shape, f32 out) ----------------
__global__ __launch_bounds__(256) void k_alpha1(const int* __restrict__ offsets,
                                                const int* __restrict__ csr_src,
                                                const float* __restrict__ aS,
                                                const float* __restrict__ aD,
                                                float* __restrict__ alphaF,
                                                float* __restrict__ selfA, int N) {
    int n = blockIdx.x * 4 + (threadIdx.x >> 6);
    if (n >= N) return;
    int lane = threadIdx.x & 63;
    float4 aDn = *(const float4*)(aD + (size_t)n * 4);
    float4 aSn = *(const float4*)(aS + (size_t)n * 4);
    float r0 = 0.f, r1 = 0.f, r2 = 0.f, r3 = 0.f;
    int b = offsets[n], e = offsets[n + 1];
    for (int i = b + lane; i < e; i += 64) {
        int s = csr_src[i];
        float4 v = *(const float4*)(aS + (size_t)s * 4);
        r0 += __expf(lrelu(v.x + aDn.x));
        r1 += __expf(lrelu(v.y + aDn.y));
        r2 += __expf(lrelu(v.z + aDn.z));
        r3 += __expf(lrelu(v.w + aDn.w));
    }
#pragma unroll
    for (int m = 1; m < 64; m <<= 1) {
        r0 += __shfl_xor(r0, m);
        r1 += __shfl_xor(r1, m);
        r2 += __shfl_xor(r2, m);
        r3 += __shfl_xor(r3, m);
    }
    float w0 = __expf(lrelu(aSn.x + aDn.x));
    float w1 = __expf(lrelu(aSn.y + aDn.y));
    float w2 = __expf(lrelu(aSn.z + aDn.z));
    float w3 = __expf(lrelu(aSn.w + aDn.w));
    float i0 = 1.f / (r0 + w0), i1 = 1.f / (r1 + w1), i2 = 1.f / (r2 + w2), i3 = 1.f / (r3 + w3);
    if (lane == 0)
        *(float4*)(selfA + (size_t)n * 4) = make_float4(w0 * i0, w1 * i1, w2 * i2, w3 * i3);
    for (int i = b + lane; i < e; i += 64) {
        int s = csr_src[i];
        float4 v = *(const float4*)(aS + (size_t)s * 4);
        float4 al;
        al.x = __expf(lrelu(v.x + aDn.x)) * i0;
        al.y = __expf(lrelu(v.y + aDn.y)) * i1;
        al.z = __expf(lrelu(v.z + aDn.z)) * i2;
        al.w = __expf(lrelu(v.w + aDn.w)) * i3;
        *(float4*)(alphaF + (size_t)i * 4) = al;
    }
}

__global__ __launch_bounds__(256) void k_alpha2(const int* __restrict__ offsets,
                                                const int* __restrict__ csr_src,
                                                const float* __restrict__ aS,
                                                const float* __restrict__ aD,
                                                float* __restrict__ alpha,
                                                float* __restrict__ selfA, int N) {
    int n = blockIdx.x * 4 + (threadIdx.x >> 6);
    if (n >= N) return;
    int lane = threadIdx.x & 63;
    float aDn = aD[n];
    float r0 = 0.f;
    int b = offsets[n], e = offsets[n + 1];
    for (int i = b + lane; i < e; i += 64) {
        r0 += __expf(lrelu(aS[csr_src[i]] + aDn));
    }
#pragma unroll
    for (int m = 1; m < 64; m <<= 1) r0 += __shfl_xor(r0, m);
    float w0 = __expf(lrelu(aS[n] + aDn));
    float inv = 1.f / (r0 + w0);
    if (lane == 0) selfA[n] = w0 * inv;
    for (int i = b + lane; i < e; i += 64) {
        alpha[i] = __expf(lrelu(aS[csr_src[i]] + aDn)) * inv;
    }
}

// ---------------- message gather (R5-proven shape, f32 alphas) ----------------
// 1 wave/node, 2 ch/lane; unroll-4; plain vector loads (no readlane).
__global__ __launch_bounds__(256) void k_msg1(const int* __restrict__ offsets,
                                              const int* __restrict__ csr_src,
                                              const float* __restrict__ alphaF,
                                              const float* __restrict__ selfA,
                                              const f16* __restrict__ Af,
                                              const float* __restrict__ b1,
                                              f16* __restrict__ Hf, int N) {
    int n = blockIdx.x * 4 + (threadIdx.x >> 6);
    if (n >= N) return;
    int lane = threadIdx.x & 63;
    int c0 = lane * 2;
    int h = lane >> 4;
    float sa = selfA[n * 4 + h];
    float2 pv = unpack_h2(*(const unsigned*)(Af + (size_t)n * 128 + c0));
    float acc0 = sa * pv.x, acc1 = sa * pv.y;
    int b = offsets[n], e = offsets[n + 1];
    int i = b;
    for (; i + 4 <= e; i += 4) {
        int s0 = csr_src[i], s1 = csr_src[i + 1], s2 = csr_src[i + 2], s3 = csr_src[i + 3];
        float a0 = alphaF[(size_t)i * 4 + h];
        float a1 = alphaF[(size_t)(i + 1) * 4 + h];
        float a2 = alphaF[(size_t)(i + 2) * 4 + h];
        float a3 = alphaF[(size_t)(i + 3) * 4 + h];
        unsigned r0 = *(const unsigned*)(Af + (size_t)s0 * 128 + c0);
        unsigned r1 = *(const unsigned*)(Af + (size_t)s1 * 128 + c0);
        unsigned r2 = *(const unsigned*)(Af + (size_t)s2 * 128 + c0);
        unsigned r3 = *(const unsigned*)(Af + (size_t)s3 * 128 + c0);
        float2 f0 = unpack_h2(r0), f1 = unpack_h2(r1), f2 = unpack_h2(r2), f3 = unpack_h2(r3);
        acc0 = fmaf(a0, f0.x, acc0); acc1 = fmaf(a0, f0.y, acc1);
        acc0 = fmaf(a1, f1.x, acc0); acc1 = fmaf(a1, f1.y, acc1);
        acc0 = fmaf(a2, f2.x, acc0); acc1 = fmaf(a2, f2.y, acc1);
        acc0 = fmaf(a3, f3.x, acc0); acc1 = fmaf(a3, f3.y, acc1);
    }
    for (; i < e; i++) {
        int s0 = csr_src[i];
        float a0 = alphaF[(size_t)i * 4 + h];
        float2 f0 = unpack_h2(*(const unsigned*)(Af + (size_t)s0 * 128 + c0));
        acc0 = fmaf(a0, f0.x, acc0); acc1 = fmaf(a0, f0.y, acc1);
    }
    float2 bb = *(const float2*)(b1 + c0);
    *(unsigned*)(Hf + (size_t)n * 128 + c0) =
        pack_h2(fmaxf(acc0 + bb.x, 0.f), fmaxf(acc1 + bb.y, 0.f));
}

// 3 nodes per wave (20 lanes each); unroll-4 (R6-proven). Fused bias; fp32 out.
__global__ __launch_bounds__(256) void k_msg2(const int* __restrict__ offsets,
                                              const int* __restrict__ csr_src,
                                              const float* __restrict__ alpha,
                                              const float* __restrict__ selfA,
                                              const f16* __restrict__ X2f,
                                              const float* __restrict__ b2,
                                              float* __restrict__ OUT, int N) {
    int wv = threadIdx.x >> 6, lane = threadIdx.x & 63;
    if (lane >= 60) return;
    int g = lane / 20;
    int li = lane - g * 20;
    int n = blockIdx.x * 12 + wv * 3 + g;
    if (n >= N) return;
    int c0 = li * 2;
    float sa = selfA[n];
    float2 pv = unpack_h2(*(const unsigned*)(X2f + (size_t)n * 40 + c0));
    float acc0 = sa * pv.x, acc1 = sa * pv.y;
    int b = offsets[n], e = offsets[n + 1];
    int i = b;
    for (; i + 4 <= e; i += 4) {
        int s0 = csr_src[i], s1 = csr_src[i + 1], s2 = csr_src[i + 2], s3 = csr_src[i + 3];
        float a0 = alpha[i], a1 = alpha[i + 1], a2 = alpha[i + 2], a3 = alpha[i + 3];
        float2 f0 = unpack_h2(*(const unsigned*)(X2f + (size_t)s0 * 40 + c0));
        float2 f1 = unpack_h2(*(const unsigned*)(X2f + (size_t)s1 * 40 + c0));
        float2 f2 = unpack_h2(*(const unsigned*)(X2f + (size_t)s2 * 40 + c0));
        float2 f3 = unpack_h2(*(const unsigned*)(X2f + (size_t)s3 * 40 + c0));
        acc0 += a0 * f0.x + a1 * f1.x + a2 * f2.x + a3 * f3.x;
        acc1 += a0 * f0.y + a1 * f1.y + a2 * f2.y + a3 * f3.y;
    }
    for (; i < e; i++) {
        int s0 = csr_src[i];
        float a0 = alpha[i];
        float2 f0 = unpack_h2(*(const unsigned*)(X2f + (size_t)s0 * 40 + c0));
        acc0 += a0 * f0.x;
        acc1 += a0 * f0.y;
    }
    float2 bb = *(const float2*)(b2 + c0);
    *(float2*)(OUT + (size_t)n * 40 + c0) = make_float2(acc0 + bb.x, acc1 + bb.y);
}

extern "C" void kernel_launch(void* const* d_in, const int* in_sizes, int n_in,
                              void* d_out, int out_size, void* d_ws, size_t ws_size,
                              hipStream_t stream) {
    const float* x   = (const float*)d_in[0];
    const void*  ei  = d_in[1];
    const float* W1  = (const float*)d_in[2];
    const float* as1 = (const float*)d_in[3];
    const float* ad1 = (const float*)d_in[4];
    const float* b1  = (const float*)d_in[5];
    const float* W2  = (const float*)d_in[6];
    const float* as2 = (const float*)d_in[7];
    const float* ad2 = (const float*)d_in[8];
    const float* b2  = (const float*)d_in[9];
    float* out = (float*)d_out;

    const int N = in_sizes[0] / 128;
    const int E = in_sizes[1] / 2;

    // workspace layout — every array 16B-aligned; no aliasing (total ~111 MB,
    // below the ~115.6 MB R2 footprint that passed)
    char* w = (char*)d_ws;
    auto alloc = [&](size_t bytes) {
        char* p = w;
        w += (bytes + 15) & ~(size_t)15;
        return p;
    };
    int* flag      = (int*)alloc(16);
    int* offsets   = (int*)alloc((size_t)(N + 1) * 4);
    int* deg       = (int*)alloc((size_t)N * 4);
    int* rank      = (int*)alloc((size_t)E * 4);
    int* csr_src   = (int*)alloc((size_t)E * 4);
    int* blksum    = (int*)alloc(64 * 4);
    int* blkoff    = (int*)alloc(64 * 4);
    float* aS1     = (float*)alloc((size_t)N * 4 * 4);
    float* aD1     = (float*)alloc((size_t)N * 4 * 4);
    float* aS2     = (float*)alloc((size_t)N * 4);
    float* aD2     = (float*)alloc((size_t)N * 4);
    float* alphaF  = (float*)alloc((size_t)E * 4 * 4);   // f32 [E][4]
    float* alpha2F = (float*)alloc((size_t)E * 4);
    float* selfA1  = (float*)alloc((size_t)N * 4 * 4);
    float* selfA2  = (float*)alloc((size_t)N * 4);
    f16* W1t       = (f16*)alloc(128 * 128 * 2);
    f16* W2t       = (f16*)alloc(48 * 128 * 2);
    f16* Af        = (f16*)alloc((size_t)N * 128 * 2);
    f16* X2f       = (f16*)alloc((size_t)N * 40 * 2);
    f16* Hf        = (f16*)alloc((size_t)N * 128 * 2);

    k_detect<<<1, 256, 0, stream>>>((const int*)ei, 1024, flag);
    k_prep<<<88, 256, 0, stream>>>(W1, W2, W1t, W2t);

    // CSR build (shared by both layers)
    hipMemsetAsync(deg, 0, (size_t)N * 4, stream);
    k_degree<<<(E + 255) / 256, 256, 0, stream>>>(ei, flag, deg, rank, E);
    const int G = (N + 4095) / 4096;
    k_scan_blk<<<G, 1024, 0, stream>>>(deg, offsets, blksum, N);
    k_scan_top<<<1, 64, 0, stream>>>(blksum, blkoff, G);
    k_scan_add<<<(N + 255) / 256, 256, 0, stream>>>(offsets, blkoff, N);
    k_scatter<<<(E + 255) / 256, 256, 0, stream>>>(ei, flag, offsets, rank, csr_src, E);

    // layer 1
    const int gb = (N + 63) / 64;
    k_gemm1<<<gb, 256, 0, stream>>>(x, W1t, Af, N);
    k_attn1<<<(N * 4 + 255) / 256, 256, 0, stream>>>(Af, as1, ad1, aS1, aD1, N);
    k_alpha1<<<(N + 3) / 4, 256, 0, stream>>>(offsets, csr_src, aS1, aD1, alphaF, selfA1, N);
    k_msg1<<<(N + 3) / 4, 256, 0, stream>>>(offsets, csr_src, alphaF, selfA1, Af, b1, Hf, N);

    // layer 2
    k_gemm2<<<gb, 256, 0, stream>>>(Hf, W2t, X2f, N);
    k_attn2<<<(N + 255) / 256, 256, 0, stream>>>(X2f, as2, ad2, aS2, aD2, N);
    k_alpha2<<<(N + 3) / 4, 256, 0, stream>>>(offsets, csr_src, aS2, aD2, alpha2F, selfA2, N);
    k_msg2<<<(N + 11) / 12, 256, 0, stream>>>(offsets, csr_src, alpha2F, selfA2, X2f, b2, out, N);
}

// Round 10
// 396.248 us; speedup vs baseline: 36.0196x; 1.1326x over previous
//
#include <hip/hip_runtime.h>
#include <hip/hip_bf16.h>

#define NEG_SLOPE 0.2f
// s_getreg imm: (size-1)<<11 | offset<<6 | id ; HW_REG_XCC_ID = 20 (CDNA3/4)
#define HWREG_XCC_ID_FULL (((32 - 1) << 11) | (0 << 6) | 20)

typedef _Float16 f16;
typedef f16 f16x8 __attribute__((ext_vector_type(8)));
typedef float f32x4 __attribute__((ext_vector_type(4)));

__device__ __forceinline__ float lrelu(float v) { return v > 0.f ? v : NEG_SLOPE * v; }

__device__ __forceinline__ unsigned pack_h2(float a, float b) {
    union { f16 h[2]; unsigned u; } c;
    c.h[0] = (f16)a; c.h[1] = (f16)b;
    return c.u;
}
__device__ __forceinline__ float2 unpack_h2(unsigned u) {
    union { unsigned u; f16 h[2]; } c;
    c.u = u;
    return make_float2((float)c.h[0], (float)c.h[1]);
}

// Detect whether edge_index arrived as int64 (odd 32-bit words all zero) or int32.
__global__ void k_detect(const int* __restrict__ ei32, int npairs, int* flag) {
    __shared__ int found;
    if (threadIdx.x == 0) found = 0;
    __syncthreads();
    for (int i = threadIdx.x; i < npairs; i += blockDim.x) {
        if (ei32[2 * i + 1] != 0) found = 1;
    }
    __syncthreads();
    if (threadIdx.x == 0) *flag = found ? 0 : 1;   // 1 => int64
}

__device__ __forceinline__ void load_edge(const void* ei, int f64, int e, int E, int& s, int& d) {
    if (f64) {
        const long long* p = (const long long*)ei;
        s = (int)p[e];
        d = (int)p[(long long)E + e];
    } else {
        const int* p = (const int*)ei;
        s = p[e];
        d = p[E + e];
    }
}

// ---------------- CSR build (XCD-sharded histogram) ----------------
// shard = XCC_ID & 7: atomics on deg_part[shard] stay in one XCD's L2 (no
// cross-XCD line ping-pong). Masked -> ANY value is still correct; the shard
// id is stored with the rank, so scatter is deterministic.
__global__ void k_degree(const void* __restrict__ ei, const int* __restrict__ flag,
                         int* __restrict__ deg_part, int* __restrict__ rank, int N, int E) {
    int e = blockIdx.x * blockDim.x + threadIdx.x;
    if (e >= E) return;
    int s, d;
    load_edge(ei, *flag, e, E, s, d);
    int xcc = (int)(__builtin_amdgcn_s_getreg(HWREG_XCC_ID_FULL) & 7u);
    int lr = atomicAdd(&deg_part[xcc * N + d], 1);
    rank[e] = (xcc << 24) | lr;
}

// deg[d] = total over shards; deg_part[x][d] -> exclusive prefix over shards.
__global__ void k_sumdeg(int* __restrict__ deg_part, int* __restrict__ deg, int N) {
    int d = blockIdx.x * blockDim.x + threadIdx.x;
    if (d >= N) return;
    int p = 0;
#pragma unroll
    for (int x = 0; x < 8; x++) {
        int t = deg_part[x * N + d];
        deg_part[x * N + d] = p;
        p += t;
    }
    deg[d] = p;
}

__global__ __launch_bounds__(1024) void k_scan_blk(const int* __restrict__ deg,
                                                   int* __restrict__ offsets,
                                                   int* __restrict__ blksum, int N) {
    __shared__ int wsums[16];
    const int t = threadIdx.x;
    const int lane = t & 63;
    const int wid = t >> 6;
    int idx = blockIdx.x * 4096 + t * 4;
    int v0 = (idx + 0 < N) ? deg[idx + 0] : 0;
    int v1 = (idx + 1 < N) ? deg[idx + 1] : 0;
    int v2 = (idx + 2 < N) ? deg[idx + 2] : 0;
    int v3 = (idx + 3 < N) ? deg[idx + 3] : 0;
    int s1 = v0 + v1, s2 = s1 + v2, s3 = s2 + v3;
    int inc = s3;
#pragma unroll
    for (int off = 1; off < 64; off <<= 1) {
        int y = __shfl_up(inc, off);
        if (lane >= off) inc += y;
    }
    if (lane == 63) wsums[wid] = inc;
    __syncthreads();
    if (wid == 0) {
        int v = (lane < 16) ? wsums[lane] : 0;
        int wi = v;
#pragma unroll
        for (int off = 1; off < 16; off <<= 1) {
            int y = __shfl_up(wi, off);
            if (lane >= off) wi += y;
        }
        if (lane < 16) wsums[lane] = wi - v;
        if (lane == 15) blksum[blockIdx.x] = wi;
    }
    __syncthreads();
    int excl = wsums[wid] + (inc - s3);
    if (idx + 0 < N) offsets[idx + 1] = excl + v0;
    if (idx + 1 < N) offsets[idx + 2] = excl + s1;
    if (idx + 2 < N) offsets[idx + 3] = excl + s2;
    if (idx + 3 < N) offsets[idx + 4] = excl + s3;
}

__global__ void k_scan_top(const int* __restrict__ blksum, int* __restrict__ blkoff, int G) {
    int l = threadIdx.x;
    int v = (l < G) ? blksum[l] : 0;
    int inc = v;
#pragma unroll
    for (int off = 1; off < 64; off <<= 1) {
        int y = __shfl_up(inc, off);
        if (l >= off) inc += y;
    }
    if (l < G) blkoff[l] = inc - v;
}

__global__ void k_scan_add(int* __restrict__ offsets, const int* __restrict__ blkoff, int N) {
    int n = blockIdx.x * blockDim.x + threadIdx.x;
    if (n >= N) return;
    offsets[n + 1] += blkoff[n >> 12];
    if (n == 0) offsets[0] = 0;
}

// Deterministic, atomic-free: slot = offsets[d] + shard_prefix(d,xcc) + local_rank.
__global__ void k_scatter(const void* __restrict__ ei, const int* __restrict__ flag,
                          const int* __restrict__ offsets, const int* __restrict__ deg_part,
                          const int* __restrict__ rank, int* __restrict__ csr_src,
                          int N, int E) {
    int e = blockIdx.x * blockDim.x + threadIdx.x;
    if (e >= E) return;
    int s, d;
    load_edge(ei, *flag, e, E, s, d);
    int r = rank[e];
    int xcc = r >> 24;
    int lr = r & 0xFFFFFF;
    csr_src[offsets[d] + deg_part[xcc * N + d] + lr] = s;
}

// ---------------- weight prep: transposed f16 copies ----------------
__global__ void k_prep(const float* __restrict__ W1, const float* __restrict__ W2,
                       f16* __restrict__ W1t, f16* __restrict__ W2t) {
    int o = blockIdx.x * 256 + threadIdx.x;
    if (o < 128 * 128) {
        int n = o >> 7, k = o & 127;
        W1t[o] = (f16)W1[k * 128 + n];
    } else {
        int o2 = o - 128 * 128;
        if (o2 < 48 * 128) {
            int n = o2 >> 7, k = o2 & 127;
            W2t[o2] = (f16)(n < 40 ? W2[k * 40 + n] : 0.f);
        }
    }
}

// ---------------- GEMM1 (MFMA f16): Af = (f16)(X @ W1), [N][128] ----------------
__global__ __launch_bounds__(256) void k_gemm1(const float* __restrict__ X,
                                               const f16* __restrict__ W1t,
                                               f16* __restrict__ Af, int N) {
    __shared__ f16 sA[64 * 136];
    __shared__ f16 sB[128 * 136];
    const int t = threadIdx.x;
    const int row0 = blockIdx.x * 64;

    {
        int r = t >> 2, seg = t & 3;
        int row = row0 + r;
        if (row >= N) row = N - 1;
        const float4* xg = (const float4*)(X + (size_t)row * 128 + seg * 32);
        unsigned tmp[16];
#pragma unroll
        for (int j = 0; j < 8; j++) {
            float4 v = xg[j];
            tmp[2 * j]     = pack_h2(v.x, v.y);
            tmp[2 * j + 1] = pack_h2(v.z, v.w);
        }
        uint4* dst = (uint4*)&sA[r * 136 + seg * 32];
#pragma unroll
        for (int j = 0; j < 4; j++) dst[j] = ((uint4*)tmp)[j];
        int n = t >> 1, half = (t & 1) * 64;
        const uint4* src = (const uint4*)(W1t + n * 128 + half);
        uint4* dw = (uint4*)&sB[n * 136 + half];
#pragma unroll
        for (int j = 0; j < 8; j++) dw[j] = src[j];
    }
    __syncthreads();

    const int w = t >> 6, lane = t & 63, ln = lane & 15, q = lane >> 4;
    f32x4 acc[8];
#pragma unroll
    for (int c = 0; c < 8; c++) acc[c] = (f32x4){0.f, 0.f, 0.f, 0.f};

#pragma unroll
    for (int ks = 0; ks < 4; ks++) {
        f16x8 a = *(const f16x8*)&sA[(w * 16 + ln) * 136 + ks * 32 + q * 8];
#pragma unroll
        for (int c = 0; c < 8; c++) {
            f16x8 b = *(const f16x8*)&sB[(c * 16 + ln) * 136 + ks * 32 + q * 8];
            acc[c] = __builtin_amdgcn_mfma_f32_16x16x32_f16(a, b, acc[c], 0, 0, 0);
        }
    }

#pragma unroll
    for (int c = 0; c < 8; c++)
#pragma unroll
        for (int reg = 0; reg < 4; reg++) {
            int rg = row0 + w * 16 + q * 4 + reg;
            if (rg < N) Af[(size_t)rg * 128 + c * 16 + ln] = (f16)acc[c][reg];
        }
}

// ---------------- GEMM2 (MFMA f16): X2f = (f16)(Hf @ W2), [N][40] ----------------
__global__ __launch_bounds__(256) void k_gemm2(const f16* __restrict__ Hf,
                                               const f16* __restrict__ W2t,
                                               f16* __restrict__ X2f, int N) {
    __shared__ f16 sA[64 * 136];
    __shared__ f16 sB[48 * 136];
    const int t = threadIdx.x;
    const int row0 = blockIdx.x * 64;
    {
        int r = t >> 2, seg = t & 3;
        int row = row0 + r;
        if (row >= N) row = N - 1;
        const uint4* hg = (const uint4*)(Hf + (size_t)row * 128 + seg * 32);
        uint4* dst = (uint4*)&sA[r * 136 + seg * 32];
#pragma unroll
        for (int j = 0; j < 4; j++) dst[j] = hg[j];
        const uint4* wsrc = (const uint4*)W2t;
#pragma unroll
        for (int u = t; u < 768; u += 256) {
            int o = u * 8;
            int n = o >> 7, ko = o & 127;
            *(uint4*)&sB[n * 136 + ko] = wsrc[u];
        }
    }
    __syncthreads();

    const int w = t >> 6, lane = t & 63, ln = lane & 15, q = lane >> 4;
    f32x4 acc[3];
#pragma unroll
    for (int c = 0; c < 3; c++) acc[c] = (f32x4){0.f, 0.f, 0.f, 0.f};

#pragma unroll
    for (int ks = 0; ks < 4; ks++) {
        f16x8 a = *(const f16x8*)&sA[(w * 16 + ln) * 136 + ks * 32 + q * 8];
#pragma unroll
        for (int c = 0; c < 3; c++) {
            f16x8 b = *(const f16x8*)&sB[(c * 16 + ln) * 136 + ks * 32 + q * 8];
            acc[c] = __builtin_amdgcn_mfma_f32_16x16x32_f16(a, b, acc[c], 0, 0, 0);
        }
    }

#pragma unroll
    for (int c = 0; c < 3; c++) {
        int col = c * 16 + ln;
        if (col < 40) {
#pragma unroll
            for (int reg = 0; reg < 4; reg++) {
                int rg = row0 + w * 16 + q * 4 + reg;
                if (rg < N) X2f[(size_t)rg * 40 + col] = (f16)acc[c][reg];
            }
        }
    }
}

// ---------------- attention dots (from f16) ----------------
__global__ void k_attn1(const f16* __restrict__ Af, const float* __restrict__ att_s,
                        const float* __restrict__ att_d, float* __restrict__ aS,
                        float* __restrict__ aD, int N) {
    int t = blockIdx.x * blockDim.x + threadIdx.x;
    if (t >= N * 4) return;
    int n = t >> 2, h = t & 3;
    const uint4* xr = (const uint4*)(Af + (size_t)n * 128 + h * 32);
    float ss = 0.f, sd = 0.f;
#pragma unroll
    for (int j = 0; j < 4; j++) {
        uint4 p = xr[j];
        float2 a0 = unpack_h2(p.x), a1 = unpack_h2(p.y), a2 = unpack_h2(p.z), a3 = unpack_h2(p.w);
        float xv[8] = {a0.x, a0.y, a1.x, a1.y, a2.x, a2.y, a3.x, a3.y};
        const float* as_ = att_s + h * 32 + j * 8;
        const float* ad_ = att_d + h * 32 + j * 8;
#pragma unroll
        for (int qq = 0; qq < 8; qq++) {
            ss += xv[qq] * as_[qq];
            sd += xv[qq] * ad_[qq];
        }
    }
    aS[t] = ss;
    aD[t] = sd;
}

__global__ void k_attn2(const f16* __restrict__ X2f, const float* __restrict__ att_s,
                        const float* __restrict__ att_d, float* __restrict__ aS,
                        float* __restrict__ aD, int N) {
    int n = blockIdx.x * blockDim.x + threadIdx.x;
    if (n >= N) return;
    const unsigned* xr = (const unsigned*)(X2f + (size_t)n * 40);
    float ss = 0.f, sd = 0.f;
#pragma unroll
    for (int j = 0; j < 20; j++) {
        float2 v = unpack_h2(xr[j]);
        ss += v.x * att_s[2 * j] + v.y * att_s[2 * j + 1];
        sd += v.x * att_d[2 * j] + v.y * att_d[2 * j + 1];
    }
    aS[n] = ss;
    aD[n] = sd;
}

// ---------------- fused message + online softmax denominator ----------------
// 1 wave/node, 2 ch/lane; unroll-4. Accumulate unnormalized sum + wsum,
// normalize once at the end (exactly the reference math, reassociated).
__global__ __launch_bounds__(256) void k_msg1(const int* __restrict__ offsets,
                                              const int* __restrict__ csr_src,
                                              const float* __restrict__ aS,
                                              const float* __restrict__ aD,
                                              const f16* __restrict__ Af,
                                              const float* __restrict__ b1,
                                              f16* __restrict__ Hf, int N) {
    int n = blockIdx.x * 4 + (threadIdx.x >> 6);
    if (n >= N) return;
    int lane = threadIdx.x & 63;
    int c0 = lane * 2;
    int h = lane >> 4;
    float adh = aD[n * 4 + h];
    float wself = __expf(lrelu(aS[n * 4 + h] + adh));
    float2 pv = unpack_h2(*(const unsigned*)(Af + (size_t)n * 128 + c0));
    float acc0 = wself * pv.x, acc1 = wself * pv.y;
    float wsum = wself;
    int b = offsets[n], e = offsets[n + 1];
    int i = b;
    for (; i + 4 <= e; i += 4) {
        int s0 = csr_src[i], s1 = csr_src[i + 1], s2 = csr_src[i + 2], s3 = csr_src[i + 3];
        unsigned r0 = *(const unsigned*)(Af + (size_t)s0 * 128 + c0);
        unsigned r1 = *(const unsigned*)(Af + (size_t)s1 * 128 + c0);
        unsigned r2 = *(const unsigned*)(Af + (size_t)s2 * 128 + c0);
        unsigned r3 = *(const unsigned*)(Af + (size_t)s3 * 128 + c0);
        float w0 = __expf(lrelu(aS[s0 * 4 + h] + adh));
        float w1 = __expf(lrelu(aS[s1 * 4 + h] + adh));
        float w2 = __expf(lrelu(aS[s2 * 4 + h] + adh));
        float w3 = __expf(lrelu(aS[s3 * 4 + h] + adh));
        float2 f0 = unpack_h2(r0), f1 = unpack_h2(r1), f2 = unpack_h2(r2), f3 = unpack_h2(r3);
        acc0 = fmaf(w0, f0.x, acc0); acc1 = fmaf(w0, f0.y, acc1);
        acc0 = fmaf(w1, f1.x, acc0); acc1 = fmaf(w1, f1.y, acc1);
        acc0 = fmaf(w2, f2.x, acc0); acc1 = fmaf(w2, f2.y, acc1);
        acc0 = fmaf(w3, f3.x, acc0); acc1 = fmaf(w3, f3.y, acc1);
        wsum += (w0 + w1) + (w2 + w3);
    }
    for (; i < e; i++) {
        int s0 = csr_src[i];
        unsigned r0 = *(const unsigned*)(Af + (size_t)s0 * 128 + c0);
        float w0 = __expf(lrelu(aS[s0 * 4 + h] + adh));
        float2 f0 = unpack_h2(r0);
        acc0 = fmaf(w0, f0.x, acc0); acc1 = fmaf(w0, f0.y, acc1);
        wsum += w0;
    }
    float inv = 1.0f / wsum;
    float2 bb = *(const float2*)(b1 + c0);
    *(unsigned*)(Hf + (size_t)n * 128 + c0) =
        pack_h2(fmaxf(fmaf(acc0, inv, bb.x), 0.f), fmaxf(fmaf(acc1, inv, bb.y), 0.f));
}

// 3 nodes per wave (20 lanes each); unroll-4; fused wsum + bias; fp32 out.
__global__ __launch_bounds__(256) void k_msg2(const int* __restrict__ offsets,
                                              const int* __restrict__ csr_src,
                                              const float* __restrict__ aS,
                                              const float* __restrict__ aD,
                                              const f16* __restrict__ X2f,
                                              const float* __restrict__ b2,
                                              float* __restrict__ OUT, int N) {
    int wv = threadIdx.x >> 6, lane = threadIdx.x & 63;
    if (lane >= 60) return;
    int g = lane / 20;
    int li = lane - g * 20;
    int n = blockIdx.x * 12 + wv * 3 + g;
    if (n >= N) return;
    int c0 = li * 2;
    float adh = aD[n];
    float wself = __expf(lrelu(aS[n] + adh));
    float2 pv = unpack_h2(*(const unsigned*)(X2f + (size_t)n * 40 + c0));
    float acc0 = wself * pv.x, acc1 = wself * pv.y;
    float wsum = wself;
    int b = offsets[n], e = offsets[n + 1];
    int i = b;
    for (; i + 4 <= e; i += 4) {
        int s0 = csr_src[i], s1 = csr_src[i + 1], s2 = csr_src[i + 2], s3 = csr_src[i + 3];
        unsigned r0 = *(const unsigned*)(X2f + (size_t)s0 * 40 + c0);
        unsigned r1 = *(const unsigned*)(X2f + (size_t)s1 * 40 + c0);
        unsigned r2 = *(const unsigned*)(X2f + (size_t)s2 * 40 + c0);
        unsigned r3 = *(const unsigned*)(X2f + (size_t)s3 * 40 + c0);
        float w0 = __expf(lrelu(aS[s0] + adh));
        float w1 = __expf(lrelu(aS[s1] + adh));
        float w2 = __expf(lrelu(aS[s2] + adh));
        float w3 = __expf(lrelu(aS[s3] + adh));
        float2 f0 = unpack_h2(r0), f1 = unpack_h2(r1), f2 = unpack_h2(r2), f3 = unpack_h2(r3);
        acc0 = fmaf(w0, f0.x, acc0); acc1 = fmaf(w0, f0.y, acc1);
        acc0 = fmaf(w1, f1.x, acc0); acc1 = fmaf(w1, f1.y, acc1);
        acc0 = fmaf(w2, f2.x, acc0); acc1 = fmaf(w2, f2.y, acc1);
        acc0 = fmaf(w3, f3.x, acc0); acc1 = fmaf(w3, f3.y, acc1);
        wsum += (w0 + w1) + (w2 + w3);
    }
    for (; i < e; i++) {
        int s0 = csr_src[i];
        unsigned r0 = *(const unsigned*)(X2f + (size_t)s0 * 40 + c0);
        float w0 = __expf(lrelu(aS[s0] + adh));
        float2 f0 = unpack_h2(r0);
        acc0 = fmaf(w0, f0.x, acc0); acc1 = fmaf(w0, f0.y, acc1);
        wsum += w0;
    }
    float inv = 1.0f / wsum;
    float2 bb = *(const float2*)(b2 + c0);
    *(float2*)(OUT + (size_t)n * 40 + c0) =
        make_float2(fmaf(acc0, inv, bb.x), fmaf(acc1, inv, bb.y));
}

extern "C" void kernel_launch(void* const* d_in, const int* in_sizes, int n_in,
                              void* d_out, int out_size, void* d_ws, size_t ws_size,
                              hipStream_t stream) {
    const float* x   = (const float*)d_in[0];
    const void*  ei  = d_in[1];
    const float* W1  = (const float*)d_in[2];
    const float* as1 = (const float*)d_in[3];
    const float* ad1 = (const float*)d_in[4];
    const float* b1  = (const float*)d_in[5];
    const float* W2  = (const float*)d_in[6];
    const float* as2 = (const float*)d_in[7];
    const float* ad2 = (const float*)d_in[8];
    const float* b2  = (const float*)d_in[9];
    float* out = (float*)d_out;

    const int N = in_sizes[0] / 128;
    const int E = in_sizes[1] / 2;

    // workspace layout — all 16B-aligned; total ~80 MB (R9's 111 MB passed)
    char* w = (char*)d_ws;
    auto alloc = [&](size_t bytes) {
        char* p = w;
        w += (bytes + 15) & ~(size_t)15;
        return p;
    };
    int* flag      = (int*)alloc(16);
    int* offsets   = (int*)alloc((size_t)(N + 1) * 4);
    int* deg       = (int*)alloc((size_t)N * 4);
    int* deg_part  = (int*)alloc((size_t)N * 8 * 4);   // [8][N] sharded histogram
    int* rank      = (int*)alloc((size_t)E * 4);
    int* csr_src   = (int*)alloc((size_t)E * 4);
    int* blksum    = (int*)alloc(64 * 4);
    int* blkoff    = (int*)alloc(64 * 4);
    float* aS1     = (float*)alloc((size_t)N * 4 * 4);
    float* aD1     = (float*)alloc((size_t)N * 4 * 4);
    float* aS2     = (float*)alloc((size_t)N * 4);
    float* aD2     = (float*)alloc((size_t)N * 4);
    f16* W1t       = (f16*)alloc(128 * 128 * 2);
    f16* W2t       = (f16*)alloc(48 * 128 * 2);
    f16* Af        = (f16*)alloc((size_t)N * 128 * 2);
    f16* X2f       = (f16*)alloc((size_t)N * 40 * 2);
    f16* Hf        = (f16*)alloc((size_t)N * 128 * 2);

    k_detect<<<1, 256, 0, stream>>>((const int*)ei, 1024, flag);
    k_prep<<<88, 256, 0, stream>>>(W1, W2, W1t, W2t);

    // CSR build (XCD-sharded; shared by both layers)
    hipMemsetAsync(deg_part, 0, (size_t)N * 8 * 4, stream);
    k_degree<<<(E + 255) / 256, 256, 0, stream>>>(ei, flag, deg_part, rank, N, E);
    k_sumdeg<<<(N + 255) / 256, 256, 0, stream>>>(deg_part, deg, N);
    const int G = (N + 4095) / 4096;
    k_scan_blk<<<G, 1024, 0, stream>>>(deg, offsets, blksum, N);
    k_scan_top<<<1, 64, 0, stream>>>(blksum, blkoff, G);
    k_scan_add<<<(N + 255) / 256, 256, 0, stream>>>(offsets, blkoff, N);
    k_scatter<<<(E + 255) / 256, 256, 0, stream>>>(ei, flag, offsets, deg_part, rank,
                                                   csr_src, N, E);

    // layer 1
    const int gb = (N + 63) / 64;
    k_gemm1<<<gb, 256, 0, stream>>>(x, W1t, Af, N);
    k_attn1<<<(N * 4 + 255) / 256, 256, 0, stream>>>(Af, as1, ad1, aS1, aD1, N);
    k_msg1<<<(N + 3) / 4, 256, 0, stream>>>(offsets, csr_src, aS1, aD1, Af, b1, Hf, N);

    // layer 2
    k_gemm2<<<gb, 256, 0, stream>>>(Hf, W2t, X2f, N);
    k_attn2<<<(N + 255) / 256, 256, 0, stream>>>(X2f, as2, ad2, aS2, aD2, N);
    k_msg2<<<(N + 11) / 12, 256, 0, stream>>>(offsets, csr_src, aS2, aD2, X2f, b2, out, N);
}